// Round 11
// baseline (421.061 us; speedup 1.0000x reference)
//
#include <hip/hip_runtime.h>
#include <hip/hip_bf16.h>

typedef __attribute__((ext_vector_type(8))) short short8;
typedef __attribute__((ext_vector_type(8))) unsigned short ushort8;
typedef __attribute__((ext_vector_type(4))) float f32x4;

#define EPSN 1e-12f
#define GN 1024
#define GK 512

__device__ __forceinline__ float bf2f(unsigned short h) {
  union { unsigned int u; float f; } c; c.u = ((unsigned int)h) << 16; return c.f;
}
__device__ __forceinline__ unsigned short f2bf(float f) {
  union { float f; unsigned int u; } c; c.f = f;
  unsigned int u = c.u;
  return (unsigned short)((u + 0x7fffu + ((u >> 16) & 1u)) >> 16);
}
__device__ __forceinline__ float wredsum(float v) {
  v += __shfl_xor(v, 32); v += __shfl_xor(v, 16); v += __shfl_xor(v, 8);
  v += __shfl_xor(v, 4);  v += __shfl_xor(v, 2);  v += __shfl_xor(v, 1);
  return v;
}

#define GLL(g, l) __builtin_amdgcn_global_load_lds( \
    (const __attribute__((address_space(1))) unsigned int*)(g), \
    (__attribute__((address_space(3))) unsigned int*)(l), 16, 0, 0)

// ---------------- prep: normalize positive_center (1 row) + negative_centers (4 rows)
__global__ void k_prep(const float* __restrict__ pc, const float* __restrict__ nc,
                       float* __restrict__ pos_hat, float* __restrict__ negc0_hat) {
  int tid = threadIdx.x, lane = tid & 63, w = tid >> 6; // 5 waves
  const float* src = (w == 0) ? pc : (nc + (w - 1) * 512);
  float* dst = (w == 0) ? pos_hat : (negc0_hat + (w - 1) * 512);
  float4 a = *(const float4*)(src + lane * 8);
  float4 b = *(const float4*)(src + lane * 8 + 4);
  float x[8] = {a.x,a.y,a.z,a.w,b.x,b.y,b.z,b.w};
  float ss = 0.f;
  #pragma unroll
  for (int j = 0; j < 8; j++) ss += x[j]*x[j];
  ss = wredsum(ss);
  float inv = 1.f / fmaxf(sqrtf(ss), EPSN);
  #pragma unroll
  for (int j = 0; j < 8; j++) dst[lane*8+j] = x[j]*inv;
}

// ---------------- generic column reduce: R[col] = sum_r P[r][col]; grid = ncols/16
__global__ __launch_bounds__(256) void k_redcol(const float* __restrict__ P, float* __restrict__ R,
                                                int nrows, int ncols) {
  __shared__ float lred[64];
  int tid = threadIdx.x, lane = tid & 63, w = tid >> 6;
  int colg = blockIdx.x * 16;
  int ci = tid & 15;
  int r0 = tid >> 4; // 0..15
  float s = 0.f;
  for (int r = r0; r < nrows; r += 16)
    s += P[(size_t)r * ncols + colg + ci];
  s += __shfl_xor(s, 16); s += __shfl_xor(s, 32);
  if (lane < 16) lred[w * 16 + lane] = s;
  __syncthreads();
  if (tid < 16) R[colg + tid] = lred[tid] + lred[16 + tid] + lred[32 + tid] + lred[48 + tid];
}

// ---------------- row norms for proxy: RAW bf16 cast + 1/||row||
__global__ __launch_bounds__(256) void k_rownormP(const float* __restrict__ X,
                                                  unsigned short* __restrict__ Y,
                                                  float* __restrict__ invn, int rows) {
  int lane = threadIdx.x & 63;
  int w0 = blockIdx.x * 4 + (threadIdx.x >> 6);
  int nw = gridDim.x * 4;
  for (int row = w0; row < rows; row += nw) {
    const float* src = X + (size_t)row * 512 + lane * 8;
    float4 a = *(const float4*)src;
    float4 b = *(const float4*)(src + 4);
    float x[8] = {a.x,a.y,a.z,a.w,b.x,b.y,b.z,b.w};
    float ss = 0.f;
    #pragma unroll
    for (int j = 0; j < 8; j++) ss += x[j]*x[j];
    ss = wredsum(ss);
    float inv = 1.f / fmaxf(sqrtf(ss), EPSN);
    if (lane == 0) invn[row] = inv;
    ushort8 o;
    #pragma unroll
    for (int j = 0; j < 8; j++) o[j] = f2bf(x[j]);
    *(ushort8*)(Y + (size_t)row * 512 + lane * 8) = o;
  }
}

// ---------------- FUSED: blocks 0..511 = ploss partials; 512..1535 = nstats; 32 rows/block each
__global__ __launch_bounds__(256) void k_plns(const float* __restrict__ PF, const float* __restrict__ ph_g,
                                              float* __restrict__ PlossP,
                                              const float* __restrict__ NF, const float* __restrict__ nch0,
                                              float* __restrict__ inv_n, float* __restrict__ CntP,
                                              float* __restrict__ SumP) {
  __shared__ float fl[8192]; // nstats: [4 waves][4][512]
  __shared__ float cb[16];
  int tid = threadIdx.x, lane = tid & 63, w = tid >> 6;
  if (blockIdx.x < 512) {
    // ---- ploss path
    float ph[8];
    #pragma unroll
    for (int j = 0; j < 8; j++) ph[j] = ph_g[lane*8+j];
    float lsum = 0.f;
    int row0 = blockIdx.x * 32;
    for (int rr = w; rr < 32; rr += 4) {
      int row = row0 + rr;
      const float* src = PF + (size_t)row * 512 + lane * 8;
      float4 a = *(const float4*)src;
      float4 b = *(const float4*)(src + 4);
      float x[8] = {a.x,a.y,a.z,a.w,b.x,b.y,b.z,b.w};
      float ss = 0.f, dp = 0.f;
      #pragma unroll
      for (int j = 0; j < 8; j++) { ss += x[j]*x[j]; dp += x[j]*ph[j]; }
      ss = wredsum(ss); dp = wredsum(dp);
      if (lane == 0) lsum += dp / fmaxf(sqrtf(ss), EPSN);
    }
    if (lane == 0) cb[w] = lsum;
    __syncthreads();
    if (tid == 0) PlossP[blockIdx.x] = cb[0]+cb[1]+cb[2]+cb[3];
    return;
  }
  // ---- nstats path
  const int nb = blockIdx.x - 512;
  float ph[8], nh[4][8];
  #pragma unroll
  for (int j = 0; j < 8; j++) ph[j] = ph_g[lane*8+j];
  #pragma unroll
  for (int c = 0; c < 4; c++)
    #pragma unroll
    for (int j = 0; j < 8; j++) nh[c][j] = nch0[c*512 + lane*8 + j];
  float acc[4][8];
  float cnt[4] = {0.f,0.f,0.f,0.f};
  #pragma unroll
  for (int c = 0; c < 4; c++)
    #pragma unroll
    for (int j = 0; j < 8; j++) acc[c][j] = 0.f;
  int row0 = nb * 32;
  for (int rr = w; rr < 32; rr += 4) {
    int row = row0 + rr;
    const float* src = NF + (size_t)row * 512 + lane * 8;
    float4 a = *(const float4*)src;
    float4 b = *(const float4*)(src + 4);
    float x[8] = {a.x,a.y,a.z,a.w,b.x,b.y,b.z,b.w};
    float ss = 0.f, dp = 0.f, dn[4] = {0.f,0.f,0.f,0.f};
    #pragma unroll
    for (int j = 0; j < 8; j++) {
      ss += x[j]*x[j]; dp += x[j]*ph[j];
      #pragma unroll
      for (int c = 0; c < 4; c++) dn[c] += x[j]*nh[c][j];
    }
    ss = wredsum(ss); dp = wredsum(dp);
    #pragma unroll
    for (int c = 0; c < 4; c++) dn[c] = wredsum(dn[c]);
    float inv = 1.f / fmaxf(sqrtf(ss), EPSN);
    if (lane == 0) inv_n[row] = inv;
    float sp = dp * inv;
    float s0 = dn[0]*inv, s1 = dn[1]*inv, s2 = dn[2]*inv, s3 = dn[3]*inv;
    int am = 0; float best = s0;
    if (s1 > best) { best = s1; am = 1; }
    if (s2 > best) { best = s2; am = 2; }
    if (s3 > best) { best = s3; am = 3; }
    float kf = (sp < 0.7f) ? 1.f : 0.f;
    #pragma unroll
    for (int c = 0; c < 4; c++) {
      float m = (am == c) ? kf : 0.f;
      #pragma unroll
      for (int j = 0; j < 8; j++) acc[c][j] += m * x[j];
      if (lane == 0) cnt[c] += m;
    }
  }
  #pragma unroll
  for (int c = 0; c < 4; c++)
    #pragma unroll
    for (int j = 0; j < 8; j++) fl[w*2048 + c*512 + lane*8 + j] = acc[c][j];
  if (lane == 0) {
    #pragma unroll
    for (int c = 0; c < 4; c++) cb[w*4+c] = cnt[c];
  }
  __syncthreads();
  for (int q = tid; q < 2048; q += 256)
    SumP[(size_t)nb * 2048 + q] = fl[q] + fl[2048+q] + fl[4096+q] + fl[6144+q];
  if (tid < 4) CntP[nb * 4 + tid] = cb[tid] + cb[4+tid] + cb[8+tid] + cb[12+tid];
}

// ---------------- center update + repulsion (single block, wave per cluster)
__global__ void k_center(const float* __restrict__ CntP, const float* __restrict__ sums,
                         const float* __restrict__ negc_raw, const float* __restrict__ pos_hat,
                         float* __restrict__ negc_hat, float* __restrict__ scal) {
  __shared__ float hbuf[2048];
  __shared__ float spn[4];
  __shared__ float snn[16];
  int tid = threadIdx.x, lane = tid & 63, c = tid >> 6;
  float cs = 0.f;
  for (int r = lane; r < 1024; r += 64) cs += CntP[r*4 + c];
  float cnt = wredsum(cs);
  float x[8], raw[8], ph[8];
  #pragma unroll
  for (int j = 0; j < 8; j++) {
    x[j] = sums[c*512 + lane*8 + j] / fmaxf(cnt, 1.f);
    raw[j] = negc_raw[c*512 + lane*8 + j];
    ph[j] = pos_hat[lane*8 + j];
  }
  float ss = 0.f;
  #pragma unroll
  for (int j = 0; j < 8; j++) ss += x[j]*x[j];
  ss = wredsum(ss);
  float n1 = fmaxf(sqrtf(ss), EPSN);
  #pragma unroll
  for (int j = 0; j < 8; j++) x[j] = raw[j] + (x[j]/n1 - raw[j]) * 0.1f;
  ss = 0.f;
  #pragma unroll
  for (int j = 0; j < 8; j++) ss += x[j]*x[j];
  ss = wredsum(ss);
  float n2 = fmaxf(sqrtf(ss), EPSN);
  bool upd = (cnt >= 3.0f);
  #pragma unroll
  for (int j = 0; j < 8; j++) x[j] = upd ? (x[j]/n2) : raw[j];
  ss = 0.f;
  #pragma unroll
  for (int j = 0; j < 8; j++) ss += x[j]*x[j];
  ss = wredsum(ss);
  float n3 = fmaxf(sqrtf(ss), EPSN);
  float dp = 0.f;
  #pragma unroll
  for (int j = 0; j < 8; j++) {
    x[j] = x[j] / n3;
    negc_hat[c*512 + lane*8 + j] = x[j];
    hbuf[c*512 + lane*8 + j] = x[j];
    dp += x[j] * ph[j];
  }
  dp = wredsum(dp);
  if (lane == 0) spn[c] = dp;
  __syncthreads();
  float d4[4] = {0.f,0.f,0.f,0.f};
  #pragma unroll
  for (int c2 = 0; c2 < 4; c2++) {
    float d = 0.f;
    #pragma unroll
    for (int j = 0; j < 8; j++) d += x[j] * hbuf[c2*512 + lane*8 + j];
    d4[c2] = wredsum(d);
  }
  if (lane == 0) {
    #pragma unroll
    for (int c2 = 0; c2 < 4; c2++) snn[c*4 + c2] = d4[c2];
  }
  __syncthreads();
  if (tid == 0) {
    float rep_np = 0.f;
    for (int i = 0; i < 4; i++) rep_np += logf(fmaxf(1.f - spn[i], 1e-6f));
    rep_np = -rep_np * 0.25f;
    float rep_nn = 0.f;
    for (int i = 0; i < 4; i++)
      for (int j2 = 0; j2 < 4; j2++)
        if (i != j2) rep_nn += logf(fmaxf(1.f - snn[i*4+j2], 1e-6f));
    rep_nn = -rep_nn / 12.f;
    scal[4] = rep_np + 0.1f * rep_nn;
  }
}

// ---------------- FUSED: blocks 0..1023 = nloss; 1024..3071 = upass; 32 rows/block each
__global__ __launch_bounds__(256) void k_nlup(const float* __restrict__ NF, const float* __restrict__ inv_n,
                                              const float* __restrict__ nch, float* __restrict__ NlossP,
                                              const float* __restrict__ U, float* __restrict__ SU,
                                              float* __restrict__ UPp, unsigned short* __restrict__ Uh,
                                              float* __restrict__ invU) {
  __shared__ float sh[16];
  int tid = threadIdx.x, lane = tid & 63, w = tid >> 6;
  float nh[4][8];
  #pragma unroll
  for (int c = 0; c < 4; c++)
    #pragma unroll
    for (int j = 0; j < 8; j++) nh[c][j] = nch[c*512 + lane*8 + j];
  if (blockIdx.x < 1024) {
    // ---- nloss path
    float lsum = 0.f;
    int row0 = blockIdx.x * 32;
    for (int rr = w; rr < 32; rr += 4) {
      int row = row0 + rr;
      const float* src = NF + (size_t)row * 512 + lane * 8;
      float4 a = *(const float4*)src;
      float4 b = *(const float4*)(src + 4);
      float x[8] = {a.x,a.y,a.z,a.w,b.x,b.y,b.z,b.w};
      float dn[4] = {0.f,0.f,0.f,0.f};
      #pragma unroll
      for (int j = 0; j < 8; j++)
        #pragma unroll
        for (int c = 0; c < 4; c++) dn[c] += x[j]*nh[c][j];
      #pragma unroll
      for (int c = 0; c < 4; c++) dn[c] = wredsum(dn[c]);
      if (lane == 0) {
        float inv = inv_n[row];
        float s0 = dn[0]*inv, s1 = dn[1]*inv, s2 = dn[2]*inv, s3 = dn[3]*inv;
        float mx = fmaxf(fmaxf(s0,s1), fmaxf(s2,s3));
        float e0 = __expf(s0-mx), e1 = __expf(s1-mx), e2 = __expf(s2-mx), e3 = __expf(s3-mx);
        float Z = e0+e1+e2+e3;
        lsum += (mx + logf(Z)) - (e0*s0+e1*s1+e2*s2+e3*s3)/Z;
      }
    }
    if (lane == 0) sh[w] = lsum;
    __syncthreads();
    if (tid == 0) NlossP[blockIdx.x] = sh[0]+sh[1]+sh[2]+sh[3];
    return;
  }
  // ---- upass path
  const int ub = blockIdx.x - 1024;
  float eacc[4] = {0.f,0.f,0.f,0.f};
  int row0 = ub * 32;
  for (int rr = w; rr < 32; rr += 4) {
    int row = row0 + rr;
    const float* src = U + (size_t)row * 512 + lane * 8;
    float4 a = *(const float4*)src;
    float4 b = *(const float4*)(src + 4);
    float x[8] = {a.x,a.y,a.z,a.w,b.x,b.y,b.z,b.w};
    float ss = 0.f, dn[4] = {0.f,0.f,0.f,0.f};
    #pragma unroll
    for (int j = 0; j < 8; j++) {
      ss += x[j]*x[j];
      #pragma unroll
      for (int c = 0; c < 4; c++) dn[c] += x[j]*nh[c][j];
    }
    ss = wredsum(ss);
    #pragma unroll
    for (int c = 0; c < 4; c++) dn[c] = wredsum(dn[c]);
    float inv = 1.f / fmaxf(sqrtf(ss), EPSN);
    ushort8 o;
    #pragma unroll
    for (int j = 0; j < 8; j++) o[j] = f2bf(x[j]);   // RAW cast; normalized in GEMM epilogue
    *(ushort8*)(Uh + (size_t)row * 512 + lane * 8) = o;
    if (lane == 0) {
      invU[row] = inv;
      float4 sv; sv.x = dn[0]*inv; sv.y = dn[1]*inv; sv.z = dn[2]*inv; sv.w = dn[3]*inv;
      *(float4*)(SU + (size_t)row * 4) = sv;
      eacc[0] += __expf(20.f*sv.x); eacc[1] += __expf(20.f*sv.y);
      eacc[2] += __expf(20.f*sv.z); eacc[3] += __expf(20.f*sv.w);
    }
  }
  if (lane == 0) {
    #pragma unroll
    for (int c = 0; c < 4; c++) sh[w*4+c] = eacc[c];
  }
  __syncthreads();
  if (tid < 4) UPp[ub * 4 + tid] = sh[tid] + sh[4+tid] + sh[8+tid] + sh[12+tid];
}

// ---------------- pseudo sinkhorn pass over [65536][4] f32; Rin = sum of Pin[n_in][4] partials
__global__ __launch_bounds__(256) void k_psink(const float* __restrict__ SU, const float* __restrict__ Pin,
                                               int n_in, float* __restrict__ Pout,
                                               float* __restrict__ PLout, int mode) {
  __shared__ float lr[16];
  int tid = threadIdx.x, lane = tid & 63, w = tid >> 6;
  float i0 = 0.f, i1 = 0.f, i2 = 0.f, i3 = 0.f;
  for (int r = tid; r < n_in; r += 256) {
    float4 v = *(const float4*)(Pin + (size_t)r * 4);
    i0 += v.x; i1 += v.y; i2 += v.z; i3 += v.w;
  }
  i0 = wredsum(i0); i1 = wredsum(i1); i2 = wredsum(i2); i3 = wredsum(i3);
  if (lane == 0) { lr[w*4+0] = i0; lr[w*4+1] = i1; lr[w*4+2] = i2; lr[w*4+3] = i3; }
  __syncthreads();
  float R0 = lr[0]+lr[4]+lr[8]+lr[12];
  float R1_ = lr[1]+lr[5]+lr[9]+lr[13];
  float R2_ = lr[2]+lr[6]+lr[10]+lr[14];
  float R3_ = lr[3]+lr[7]+lr[11]+lr[15];
  float r0 = 1.f/(4.f*R0), r1 = 1.f/(4.f*R1_), r2 = 1.f/(4.f*R2_), r3 = 1.f/(4.f*R3_);
  float a0 = 0.f, a1 = 0.f, a2 = 0.f, a3 = 0.f, lsum = 0.f;
  int row = blockIdx.x * blockDim.x + threadIdx.x;
  {
    float4 s = *(const float4*)(SU + (size_t)row * 4);
    float x0 = __expf(20.f*s.x), x1 = __expf(20.f*s.y);
    float x2 = __expf(20.f*s.z), x3 = __expf(20.f*s.w);
    float E0 = x0*r0, E1 = x1*r1, E2 = x2*r2, E3 = x3*r3;
    float cf = 1.f / ((E0+E1+E2+E3) * 65536.f);
    if (mode == 1) { a0 = x0*cf; a1 = x1*cf; a2 = x2*cf; a3 = x3*cf; }
    else {
      float term = (E0*s.x + E1*s.y + E2*s.z + E3*s.w) * 65536.f * cf;
      float mx = fmaxf(fmaxf(s.x,s.y), fmaxf(s.z,s.w));
      float z = __expf(s.x-mx)+__expf(s.y-mx)+__expf(s.z-mx)+__expf(s.w-mx);
      lsum = (mx + logf(z)) - term;
    }
  }
  __syncthreads();
  if (mode == 1) {
    a0 = wredsum(a0); a1 = wredsum(a1); a2 = wredsum(a2); a3 = wredsum(a3);
    if (lane == 0) { lr[w*4+0] = a0; lr[w*4+1] = a1; lr[w*4+2] = a2; lr[w*4+3] = a3; }
    __syncthreads();
    if (tid < 4) Pout[blockIdx.x * 4 + tid] = lr[tid] + lr[4+tid] + lr[8+tid] + lr[12+tid];
  } else {
    lsum = wredsum(lsum);
    if (lane == 0) lr[w] = lsum;
    __syncthreads();
    if (tid == 0) PLout[blockIdx.x] = lr[0]+lr[1]+lr[2]+lr[3];
  }
}

// ---------------- bf16 GEMM: 256x128 tile, 8 waves, BK=32 double-buffered with
// counted vmcnt + RAW s_barrier pipeline (T3/T4 minimum form; no vmcnt(0) drains in loop)
// and chunk-XOR LDS swizzle (conflict-free at 64B row stride; both-sides per rule #21).
__global__ __launch_bounds__(512) void k_gemm(const unsigned short* __restrict__ A,
                                              const unsigned short* __restrict__ B,
                                              const float* __restrict__ invU,
                                              const float* __restrict__ invP,
                                              unsigned short* __restrict__ S,
                                              float* __restrict__ R1) {
  __shared__ unsigned short lAB[24576]; // 2 x 12288 shorts (A[256][32]+B[128][32]); epilogue C[128][136]
  __shared__ float red[1024];
  const int swz = (blockIdx.x & 7) * 256 + (blockIdx.x >> 3);
  const int rowblk = swz >> 3, colblk = swz & 7;
  const int tid = threadIdx.x, lane = tid & 63;
  const int wid = tid >> 6, wm = wid >> 1, wn = wid & 1;
  f32x4 acc[4][4];
  #pragma unroll
  for (int m = 0; m < 4; m++)
    #pragma unroll
    for (int n = 0; n < 4; n++) acc[m][n] = (f32x4){0.f,0.f,0.f,0.f};
  const unsigned short* Ag = A + (size_t)rowblk * 256 * GK;
  const unsigned short* Bg = B + (size_t)colblk * 128 * GK;
  const int sr = tid >> 2;                               // staged row 0..127
  const int sc = ((tid & 3) ^ ((sr >> 1) & 3)) * 8;      // pre-swizzled source chunk
  // fragment read rows/chunks (swizzled with same involution)
  int rA[4], cAo[4], rB[4], cBo[4];
  #pragma unroll
  for (int m = 0; m < 4; m++) {
    rA[m] = wm*64 + m*16 + (lane & 15);
    cAo[m] = rA[m]*32 + (((lane >> 4) ^ ((rA[m] >> 1) & 3)) * 8);
  }
  #pragma unroll
  for (int n = 0; n < 4; n++) {
    rB[n] = wn*64 + n*16 + (lane & 15);
    cBo[n] = 8192 + rB[n]*32 + (((lane >> 4) ^ ((rB[n] >> 1) & 3)) * 8);
  }
  // prologue: stage tiles 0 and 1
  #pragma unroll
  for (int t = 0; t < 2; t++) {
    unsigned short* nb = lAB + t * 12288;
    const int kt = t * 32;
    GLL(Ag + (size_t)sr * GK + kt + sc,         nb + tid * 8);
    GLL(Ag + (size_t)(sr + 128) * GK + kt + sc, nb + (512 + tid) * 8);
    GLL(Bg + (size_t)sr * GK + kt + sc,         nb + (1024 + tid) * 8);
  }
  for (int t = 0; t < 15; t++) {
    asm volatile("s_waitcnt vmcnt(3)" ::: "memory");   // tile t's 3 GLLs landed (t+1 stays in flight)
    __builtin_amdgcn_s_barrier();
    asm volatile("" ::: "memory");
    const unsigned short* cb = lAB + (t & 1) * 12288;
    short8 af[4], bf[4];
    #pragma unroll
    for (int m = 0; m < 4; m++) af[m] = *(const short8*)(cb + cAo[m]);
    #pragma unroll
    for (int n = 0; n < 4; n++) bf[n] = *(const short8*)(cb + cBo[n]);
    #pragma unroll
    for (int m = 0; m < 4; m++)
      #pragma unroll
      for (int n = 0; n < 4; n++)
        acc[m][n] = __builtin_amdgcn_mfma_f32_16x16x32_bf16(af[m], bf[n], acc[m][n], 0, 0, 0);
    asm volatile("" ::: "memory");
    __builtin_amdgcn_s_barrier();                      // all reads of buf[t&1] retired
    asm volatile("" ::: "memory");
    if (t < 14) {                                      // restage into the buffer just consumed
      unsigned short* nb = lAB + (t & 1) * 12288;
      const int kt = (t + 2) * 32;
      GLL(Ag + (size_t)sr * GK + kt + sc,         nb + tid * 8);
      GLL(Ag + (size_t)(sr + 128) * GK + kt + sc, nb + (512 + tid) * 8);
      GLL(Bg + (size_t)sr * GK + kt + sc,         nb + (1024 + tid) * 8);
    }
  }
  // final tile 15
  asm volatile("s_waitcnt vmcnt(0)" ::: "memory");
  __builtin_amdgcn_s_barrier();
  asm volatile("" ::: "memory");
  {
    const unsigned short* cb = lAB + 12288;            // 15 & 1 = 1
    short8 af[4], bf[4];
    #pragma unroll
    for (int m = 0; m < 4; m++) af[m] = *(const short8*)(cb + cAo[m]);
    #pragma unroll
    for (int n = 0; n < 4; n++) bf[n] = *(const short8*)(cb + cBo[n]);
    #pragma unroll
    for (int m = 0; m < 4; m++)
      #pragma unroll
      for (int n = 0; n < 4; n++)
        acc[m][n] = __builtin_amdgcn_mfma_f32_16x16x32_bf16(af[m], bf[n], acc[m][n], 0, 0, 0);
  }
  __syncthreads();
  // epilogue in two 128-row halves, reusing staging LDS as C[128][136]
  unsigned short* lC = lAB;
  float racc[16];
  #pragma unroll
  for (int j = 0; j < 16; j++) racc[j] = 0.f;
  const size_t outbase = (size_t)rowblk * 256 * GN + (size_t)colblk * 128;
  const int ch8 = lane & 7, rsub = lane >> 3;
  #pragma unroll
  for (int h = 0; h < 2; h++) {
    if ((wm >> 1) == h) {
      #pragma unroll
      for (int m = 0; m < 4; m++)
        #pragma unroll
        for (int n = 0; n < 4; n++) {
          int col = wn*64 + n*16 + (lane & 15);
          float ip = invP[colblk * 128 + col];
          #pragma unroll
          for (int r = 0; r < 4; r++) {
            int lr2 = (wm & 1)*64 + m*16 + ((lane >> 4) << 2) + r;
            float iu = invU[rowblk * 256 + h*128 + lr2];
            lC[lr2 * 136 + col] = f2bf(acc[m][n][r] * iu * ip);
          }
        }
    }
    __syncthreads();
    #pragma unroll
    for (int it = 0; it < 2; it++) {
      int lr2 = it*64 + wid*8 + rsub;
      int grow = h*128 + lr2;
      ushort8 v0 = *(const ushort8*)(lC + lr2 * 136 + ch8 * 8);
      ushort8 v1 = *(const ushort8*)(lC + lr2 * 136 + 64 + ch8 * 8);
      *(short8*)(S + outbase + (size_t)grow * GN + ch8 * 8) = (short8)v0;
      *(short8*)(S + outbase + (size_t)grow * GN + 64 + ch8 * 8) = (short8)v1;
      #pragma unroll
      for (int j = 0; j < 8; j++) {
        racc[j]     += __expf(20.f * bf2f(v0[j]));
        racc[8 + j] += __expf(20.f * bf2f(v1[j]));
      }
    }
    __syncthreads();
  }
  #pragma unroll
  for (int j = 0; j < 16; j++) {
    racc[j] += __shfl_xor(racc[j], 8);
    racc[j] += __shfl_xor(racc[j], 16);
    racc[j] += __shfl_xor(racc[j], 32);
  }
  if (lane < 8) {
    #pragma unroll
    for (int j = 0; j < 8; j++) {
      red[wid * 128 + lane * 8 + j]      = racc[j];
      red[wid * 128 + 64 + lane * 8 + j] = racc[8 + j];
    }
  }
  __syncthreads();
  if (tid < 128) {
    float s8 = 0.f;
    #pragma unroll
    for (int i = 0; i < 8; i++) s8 += red[i * 128 + tid];
    int gcol = colblk * 128 + tid;
    int q = (gcol & 15) * 64 + (gcol >> 4);
    atomicAdd(&R1[q], s8);
  }
}

// ---------------- sinkhorn col-pass over sim bf16 [65536][1024]; 2-row ILP; 32 rows/block
__global__ __launch_bounds__(256) void k_sink1(const unsigned short* __restrict__ S,
                                               const float* __restrict__ Rin,
                                               float* __restrict__ Pout) {
  __shared__ float lds[4096];
  int tid = threadIdx.x, lane = tid & 63, w = tid >> 6;
  float rj[16];
  #pragma unroll
  for (int j = 0; j < 16; j++) rj[j] = 1.f / (1024.f * Rin[j*64 + lane]);
  float acc[16];
  #pragma unroll
  for (int j = 0; j < 16; j++) acc[j] = 0.f;
  int row0 = blockIdx.x * 32;
  for (int rr = w; rr < 16; rr += 4) {
    const unsigned short* SrA = S + (size_t)(row0 + rr) * 1024 + lane * 16;
    const unsigned short* SrB = S + (size_t)(row0 + rr + 16) * 1024 + lane * 16;
    ushort8 a0 = *(const ushort8*)SrA, a1 = *(const ushort8*)(SrA + 8);
    ushort8 b0 = *(const ushort8*)SrB, b1 = *(const ushort8*)(SrB + 8);
    float XA[16], XB[16];
    float csA = 0.f, csB = 0.f;
    #pragma unroll
    for (int j = 0; j < 8; j++) {
      XA[j]   = __expf(20.f * bf2f(a0[j]));
      XA[8+j] = __expf(20.f * bf2f(a1[j]));
      XB[j]   = __expf(20.f * bf2f(b0[j]));
      XB[8+j] = __expf(20.f * bf2f(b1[j]));
    }
    #pragma unroll
    for (int j = 0; j < 16; j++) { csA += XA[j]*rj[j]; csB += XB[j]*rj[j]; }
    #pragma unroll
    for (int d = 32; d >= 1; d >>= 1) {
      csA += __shfl_xor(csA, d);
      csB += __shfl_xor(csB, d);
    }
    float cfA = 1.f / (csA * 65536.f), cfB = 1.f / (csB * 65536.f);
    #pragma unroll
    for (int j = 0; j < 16; j++) acc[j] += XA[j]*cfA + XB[j]*cfB;
  }
  #pragma unroll
  for (int j = 0; j < 16; j++) lds[w*1024 + lane + 64*j] = acc[j];
  __syncthreads();
  for (int q = tid; q < 1024; q += 256)
    Pout[(size_t)blockIdx.x * 1024 + q] = lds[q] + lds[1024+q] + lds[2048+q] + lds[3072+q];
}

// ---------------- sinkhorn loss pass; 2-row ILP; lse(10s)=log(sum exp(10s)) (10s<=~10.2, safe)
__global__ __launch_bounds__(256) void k_sinkL(const unsigned short* __restrict__ S,
                                               const float* __restrict__ Rin,
                                               float* __restrict__ LPout) {
  __shared__ float lr[4];
  int tid = threadIdx.x, lane = tid & 63, w = tid >> 6;
  float rj[16];
  #pragma unroll
  for (int j = 0; j < 16; j++) rj[j] = 1.f / (1024.f * Rin[j*64 + lane]);
  float lsum = 0.f;
  int row0 = blockIdx.x * 32;
  for (int rr = w; rr < 16; rr += 4) {
    const unsigned short* SrA = S + (size_t)(row0 + rr) * 1024 + lane * 16;
    const unsigned short* SrB = S + (size_t)(row0 + rr + 16) * 1024 + lane * 16;
    ushort8 a0 = *(const ushort8*)SrA, a1 = *(const ushort8*)(SrA + 8);
    ushort8 b0 = *(const ushort8*)SrB, b1 = *(const ushort8*)(SrB + 8);
    float sA[16], sB[16], yA[16], yB[16];
    #pragma unroll
    for (int j = 0; j < 8; j++) {
      sA[j] = bf2f(a0[j]); sA[8+j] = bf2f(a1[j]);
      sB[j] = bf2f(b0[j]); sB[8+j] = bf2f(b1[j]);
    }
    #pragma unroll
    for (int j = 0; j < 16; j++) { yA[j] = __expf(10.f*sA[j]); yB[j] = __expf(10.f*sB[j]); }
    float csA = 0.f, csB = 0.f, tA = 0.f, tB = 0.f, YA = 0.f, YB = 0.f;
    #pragma unroll
    for (int j = 0; j < 16; j++) {
      float xa = yA[j]*yA[j]*rj[j];
      float xb = yB[j]*yB[j]*rj[j];
      csA += xa; tA += xa*sA[j]; YA += yA[j];
      csB += xb; tB += xb*sB[j]; YB += yB[j];
    }
    #pragma unroll
    for (int d = 32; d >= 1; d >>= 1) {
      csA += __shfl_xor(csA, d); csB += __shfl_xor(csB, d);
      tA  += __shfl_xor(tA, d);  tB  += __shfl_xor(tB, d);
      YA  += __shfl_xor(YA, d);  YB  += __shfl_xor(YB, d);
    }
    if (lane == 0)
      lsum += (logf(YA) - 10.f*tA/csA) + (logf(YB) - 10.f*tB/csB);
  }
  if (lane == 0) lr[w] = lsum;
  __syncthreads();
  if (tid == 0) LPout[blockIdx.x] = lr[0]+lr[1]+lr[2]+lr[3];
}

// ---------------- finalize: sum all loss partials, write 5 f32 outputs
__global__ __launch_bounds__(256) void k_final(const float* __restrict__ scal,
                                               const float* __restrict__ PlossP,
                                               const float* __restrict__ NlossP,
                                               const float* __restrict__ PLp,
                                               const float* __restrict__ SLp,
                                               float* __restrict__ out) {
  __shared__ float lr[4];
  int tid = threadIdx.x, lane = tid & 63, w = tid >> 6;
  float tots[4];
  const float* arrs[4] = {PlossP, NlossP, PLp, SLp};
  const int ns[4] = {512, 1024, 256, 2048};
  for (int k = 0; k < 4; k++) {
    float s = 0.f;
    for (int i = tid; i < ns[k]; i += 256) s += arrs[k][i];
    s = wredsum(s);
    __syncthreads();
    if (lane == 0) lr[w] = s;
    __syncthreads();
    tots[k] = lr[0]+lr[1]+lr[2]+lr[3];
  }
  if (tid == 0) {
    float l   = 1.f - tots[0] / 16384.f;
    float ln  = tots[1] / 32768.f;
    float lp  = tots[2] / 65536.f;
    float ul  = tots[3] / 65536.f;
    float rep = scal[4];
    float nl  = 0.5f * (ln + lp);
    float cls = 0.45f*l + 0.3f*nl + 0.1f*ul + 0.15f*rep;
    out[0] = cls;
    out[1] = l;
    out[2] = ul;
    out[3] = nl;
    out[4] = rep;
  }
}

extern "C" void kernel_launch(void* const* d_in, const int* in_sizes, int n_in,
                              void* d_out, int out_size, void* d_ws, size_t ws_size,
                              hipStream_t stream) {
  const float* PF = (const float*)d_in[0];   // p_feats [16384][512]
  const float* UF = (const float*)d_in[1];   // u_feats [65536][512]
  const float* NF = (const float*)d_in[2];   // n_feats [32768][512]
  const float* PC = (const float*)d_in[3];   // positive_center [1][512]
  const float* PU = (const float*)d_in[4];   // proxy_u [1024][512]
  const float* NC = (const float*)d_in[5];   // negative_centers [4][512]

  char* ws = (char*)d_ws;
  const size_t WS_REQUIRED = 202736768ULL;
  if (ws_size < WS_REQUIRED) return;

  float* R1     = (float*)(ws + 0);        // 1024 f32, q-order (zeroed; gemm atomics)
  float* R2     = (float*)(ws + 4096);     // 1024 f32, q-order
  float* R3     = (float*)(ws + 8192);     // 1024 f32, q-order
  float* scal   = (float*)(ws + 12288);    // 16 f32; only [4]=repulsion used
  float* sums   = (float*)(ws + 12416);    // 2048 f32
  float* invP   = (float*)(ws + 20608);    // 1024 f32
  float* UPp    = (float*)(ws + 24704);    // [2048][4]
  float* PPpA   = (float*)(ws + 57472);    // [256][4]
  float* PPpB   = (float*)(ws + 61568);    // [256][4]
  float* PLp    = (float*)(ws + 65664);    // [256]
  float* PlossP = (float*)(ws + 66688);    // [512]
  float* NlossP = (float*)(ws + 68736);    // [1024]
  float* pos_hat   = (float*)(ws + 81024); // 512 f32
  float* negc0_hat = (float*)(ws + 83072); // 2048 f32
  float* negc_hat  = (float*)(ws + 91264); // 2048 f32
  float* invU      = (float*)(ws + 99456); // 65536 f32
  float* SU    = (float*)(ws + 361600);            // [65536][4] f32 (nlup -> psink)
  unsigned short* Ph = (unsigned short*)(ws + 361600); // [1024][512] bf16 (after psink; aliases SU)
  float* SumP = (float*)(ws + 1410176);            // [1024][2048] f32 (8 MB; plns -> redcol)
  unsigned short* Uh = (unsigned short*)(ws + 1410176); // [65536][512] bf16 (nlup -> gemm; after redcol)
  float* SPp  = (float*)(ws + 1410176);            // [2048][1024] f32 (after gemm)
  float* SLp  = (float*)(ws + 9798784);            // [2048] f32 (sinkL; after gemm, Uh dead)
  float* CntP = (float*)(ws + 9806976);            // [1024][4] f32 (plns -> center; before Uh written)
  unsigned short* S = (unsigned short*)(ws + 68519040); // [65536][1024] bf16 (gemm output)
  float* inv_n = (float*)(ws + 68519040);          // 32768 f32 — inside S region; dead before gemm writes S

  hipMemsetAsync(ws, 0, 4096, stream);  // only R1 needs zeroing (gemm atomics)

  k_prep<<<1, 320, 0, stream>>>(PC, NC, pos_hat, negc0_hat);
  k_plns<<<1536, 256, 0, stream>>>(PF, pos_hat, PlossP, NF, negc0_hat, inv_n, CntP, SumP);
  k_redcol<<<128, 256, 0, stream>>>(SumP, sums, 1024, 2048);
  k_center<<<1, 256, 0, stream>>>(CntP, sums, NC, pos_hat, negc_hat, scal);
  k_nlup<<<3072, 256, 0, stream>>>(NF, inv_n, negc_hat, NlossP, UF, SU, UPp, Uh, invU);

  // pseudo sinkhorn (K=4), partial-in partial-out
  k_psink<<<256, 256, 0, stream>>>(SU, UPp, 2048, PPpA, nullptr, 1);
  k_psink<<<256, 256, 0, stream>>>(SU, PPpA, 256, PPpB, nullptr, 1);
  k_psink<<<256, 256, 0, stream>>>(SU, PPpB, 256, nullptr, PLp, 2);

  k_rownormP<<<32, 256, 0, stream>>>(PU, Ph, invP, 1024);  // Ph overlaps dead SU

  // u branch: GEMM + 3 sinkhorn passes with partial-based column reduction
  k_gemm<<<2048, 512, 0, stream>>>(Uh, Ph, invU, invP, S, R1);
  k_sink1<<<2048, 256, 0, stream>>>(S, R1, SPp);
  k_redcol<<<64, 256, 0, stream>>>(SPp, R2, 2048, 1024);
  k_sink1<<<2048, 256, 0, stream>>>(S, R2, SPp);
  k_redcol<<<64, 256, 0, stream>>>(SPp, R3, 2048, 1024);
  k_sinkL<<<2048, 256, 0, stream>>>(S, R3, SLp);

  k_final<<<1, 256, 0, stream>>>(scal, PlossP, NlossP, PLp, SLp, (float*)d_out);
}

// Round 12
// 412.147 us; speedup vs baseline: 1.0216x; 1.0216x over previous
//
#include <hip/hip_runtime.h>
#include <hip/hip_bf16.h>

typedef __attribute__((ext_vector_type(8))) short short8;
typedef __attribute__((ext_vector_type(8))) unsigned short ushort8;
typedef __attribute__((ext_vector_type(4))) float f32x4;

#define EPSN 1e-12f
#define GN 1024
#define GK 512

__device__ __forceinline__ float bf2f(unsigned short h) {
  union { unsigned int u; float f; } c; c.u = ((unsigned int)h) << 16; return c.f;
}
__device__ __forceinline__ unsigned short f2bf(float f) {
  union { float f; unsigned int u; } c; c.f = f;
  unsigned int u = c.u;
  return (unsigned short)((u + 0x7fffu + ((u >> 16) & 1u)) >> 16);
}
__device__ __forceinline__ float wredsum(float v) {
  v += __shfl_xor(v, 32); v += __shfl_xor(v, 16); v += __shfl_xor(v, 8);
  v += __shfl_xor(v, 4);  v += __shfl_xor(v, 2);  v += __shfl_xor(v, 1);
  return v;
}

#define GLL(g, l) __builtin_amdgcn_global_load_lds( \
    (const __attribute__((address_space(1))) unsigned int*)(g), \
    (__attribute__((address_space(3))) unsigned int*)(l), 16, 0, 0)

// ---------------- prep: normalize positive_center (1 row) + negative_centers (4 rows)
__global__ void k_prep(const float* __restrict__ pc, const float* __restrict__ nc,
                       float* __restrict__ pos_hat, float* __restrict__ negc0_hat) {
  int tid = threadIdx.x, lane = tid & 63, w = tid >> 6; // 5 waves
  const float* src = (w == 0) ? pc : (nc + (w - 1) * 512);
  float* dst = (w == 0) ? pos_hat : (negc0_hat + (w - 1) * 512);
  float4 a = *(const float4*)(src + lane * 8);
  float4 b = *(const float4*)(src + lane * 8 + 4);
  float x[8] = {a.x,a.y,a.z,a.w,b.x,b.y,b.z,b.w};
  float ss = 0.f;
  #pragma unroll
  for (int j = 0; j < 8; j++) ss += x[j]*x[j];
  ss = wredsum(ss);
  float inv = 1.f / fmaxf(sqrtf(ss), EPSN);
  #pragma unroll
  for (int j = 0; j < 8; j++) dst[lane*8+j] = x[j]*inv;
}

// ---------------- generic column reduce: R[col] = sum_r P[r][col]; grid = ncols/16
__global__ __launch_bounds__(256) void k_redcol(const float* __restrict__ P, float* __restrict__ R,
                                                int nrows, int ncols) {
  __shared__ float lred[64];
  int tid = threadIdx.x, lane = tid & 63, w = tid >> 6;
  int colg = blockIdx.x * 16;
  int ci = tid & 15;
  int r0 = tid >> 4; // 0..15
  float s = 0.f;
  for (int r = r0; r < nrows; r += 16)
    s += P[(size_t)r * ncols + colg + ci];
  s += __shfl_xor(s, 16); s += __shfl_xor(s, 32);
  if (lane < 16) lred[w * 16 + lane] = s;
  __syncthreads();
  if (tid < 16) R[colg + tid] = lred[tid] + lred[16 + tid] + lred[32 + tid] + lred[48 + tid];
}

// ---------------- row norms for proxy: RAW bf16 cast + 1/||row||
__global__ __launch_bounds__(256) void k_rownormP(const float* __restrict__ X,
                                                  unsigned short* __restrict__ Y,
                                                  float* __restrict__ invn, int rows) {
  int lane = threadIdx.x & 63;
  int w0 = blockIdx.x * 4 + (threadIdx.x >> 6);
  int nw = gridDim.x * 4;
  for (int row = w0; row < rows; row += nw) {
    const float* src = X + (size_t)row * 512 + lane * 8;
    float4 a = *(const float4*)src;
    float4 b = *(const float4*)(src + 4);
    float x[8] = {a.x,a.y,a.z,a.w,b.x,b.y,b.z,b.w};
    float ss = 0.f;
    #pragma unroll
    for (int j = 0; j < 8; j++) ss += x[j]*x[j];
    ss = wredsum(ss);
    float inv = 1.f / fmaxf(sqrtf(ss), EPSN);
    if (lane == 0) invn[row] = inv;
    ushort8 o;
    #pragma unroll
    for (int j = 0; j < 8; j++) o[j] = f2bf(x[j]);
    *(ushort8*)(Y + (size_t)row * 512 + lane * 8) = o;
  }
}

// ---------------- FUSED: blocks 0..511 = ploss partials; 512..1535 = nstats; 32 rows/block each
__global__ __launch_bounds__(256) void k_plns(const float* __restrict__ PF, const float* __restrict__ ph_g,
                                              float* __restrict__ PlossP,
                                              const float* __restrict__ NF, const float* __restrict__ nch0,
                                              float* __restrict__ inv_n, float* __restrict__ CntP,
                                              float* __restrict__ SumP) {
  __shared__ float fl[8192]; // nstats: [4 waves][4][512]
  __shared__ float cb[16];
  int tid = threadIdx.x, lane = tid & 63, w = tid >> 6;
  if (blockIdx.x < 512) {
    // ---- ploss path
    float ph[8];
    #pragma unroll
    for (int j = 0; j < 8; j++) ph[j] = ph_g[lane*8+j];
    float lsum = 0.f;
    int row0 = blockIdx.x * 32;
    for (int rr = w; rr < 32; rr += 4) {
      int row = row0 + rr;
      const float* src = PF + (size_t)row * 512 + lane * 8;
      float4 a = *(const float4*)src;
      float4 b = *(const float4*)(src + 4);
      float x[8] = {a.x,a.y,a.z,a.w,b.x,b.y,b.z,b.w};
      float ss = 0.f, dp = 0.f;
      #pragma unroll
      for (int j = 0; j < 8; j++) { ss += x[j]*x[j]; dp += x[j]*ph[j]; }
      ss = wredsum(ss); dp = wredsum(dp);
      if (lane == 0) lsum += dp / fmaxf(sqrtf(ss), EPSN);
    }
    if (lane == 0) cb[w] = lsum;
    __syncthreads();
    if (tid == 0) PlossP[blockIdx.x] = cb[0]+cb[1]+cb[2]+cb[3];
    return;
  }
  // ---- nstats path
  const int nb = blockIdx.x - 512;
  float ph[8], nh[4][8];
  #pragma unroll
  for (int j = 0; j < 8; j++) ph[j] = ph_g[lane*8+j];
  #pragma unroll
  for (int c = 0; c < 4; c++)
    #pragma unroll
    for (int j = 0; j < 8; j++) nh[c][j] = nch0[c*512 + lane*8 + j];
  float acc[4][8];
  float cnt[4] = {0.f,0.f,0.f,0.f};
  #pragma unroll
  for (int c = 0; c < 4; c++)
    #pragma unroll
    for (int j = 0; j < 8; j++) acc[c][j] = 0.f;
  int row0 = nb * 32;
  for (int rr = w; rr < 32; rr += 4) {
    int row = row0 + rr;
    const float* src = NF + (size_t)row * 512 + lane * 8;
    float4 a = *(const float4*)src;
    float4 b = *(const float4*)(src + 4);
    float x[8] = {a.x,a.y,a.z,a.w,b.x,b.y,b.z,b.w};
    float ss = 0.f, dp = 0.f, dn[4] = {0.f,0.f,0.f,0.f};
    #pragma unroll
    for (int j = 0; j < 8; j++) {
      ss += x[j]*x[j]; dp += x[j]*ph[j];
      #pragma unroll
      for (int c = 0; c < 4; c++) dn[c] += x[j]*nh[c][j];
    }
    ss = wredsum(ss); dp = wredsum(dp);
    #pragma unroll
    for (int c = 0; c < 4; c++) dn[c] = wredsum(dn[c]);
    float inv = 1.f / fmaxf(sqrtf(ss), EPSN);
    if (lane == 0) inv_n[row] = inv;
    float sp = dp * inv;
    float s0 = dn[0]*inv, s1 = dn[1]*inv, s2 = dn[2]*inv, s3 = dn[3]*inv;
    int am = 0; float best = s0;
    if (s1 > best) { best = s1; am = 1; }
    if (s2 > best) { best = s2; am = 2; }
    if (s3 > best) { best = s3; am = 3; }
    float kf = (sp < 0.7f) ? 1.f : 0.f;
    #pragma unroll
    for (int c = 0; c < 4; c++) {
      float m = (am == c) ? kf : 0.f;
      #pragma unroll
      for (int j = 0; j < 8; j++) acc[c][j] += m * x[j];
      if (lane == 0) cnt[c] += m;
    }
  }
  #pragma unroll
  for (int c = 0; c < 4; c++)
    #pragma unroll
    for (int j = 0; j < 8; j++) fl[w*2048 + c*512 + lane*8 + j] = acc[c][j];
  if (lane == 0) {
    #pragma unroll
    for (int c = 0; c < 4; c++) cb[w*4+c] = cnt[c];
  }
  __syncthreads();
  for (int q = tid; q < 2048; q += 256)
    SumP[(size_t)nb * 2048 + q] = fl[q] + fl[2048+q] + fl[4096+q] + fl[6144+q];
  if (tid < 4) CntP[nb * 4 + tid] = cb[tid] + cb[4+tid] + cb[8+tid] + cb[12+tid];
}

// ---------------- center update + repulsion (single block, wave per cluster)
__global__ void k_center(const float* __restrict__ CntP, const float* __restrict__ sums,
                         const float* __restrict__ negc_raw, const float* __restrict__ pos_hat,
                         float* __restrict__ negc_hat, float* __restrict__ scal) {
  __shared__ float hbuf[2048];
  __shared__ float spn[4];
  __shared__ float snn[16];
  int tid = threadIdx.x, lane = tid & 63, c = tid >> 6;
  float cs = 0.f;
  for (int r = lane; r < 1024; r += 64) cs += CntP[r*4 + c];
  float cnt = wredsum(cs);
  float x[8], raw[8], ph[8];
  #pragma unroll
  for (int j = 0; j < 8; j++) {
    x[j] = sums[c*512 + lane*8 + j] / fmaxf(cnt, 1.f);
    raw[j] = negc_raw[c*512 + lane*8 + j];
    ph[j] = pos_hat[lane*8 + j];
  }
  float ss = 0.f;
  #pragma unroll
  for (int j = 0; j < 8; j++) ss += x[j]*x[j];
  ss = wredsum(ss);
  float n1 = fmaxf(sqrtf(ss), EPSN);
  #pragma unroll
  for (int j = 0; j < 8; j++) x[j] = raw[j] + (x[j]/n1 - raw[j]) * 0.1f;
  ss = 0.f;
  #pragma unroll
  for (int j = 0; j < 8; j++) ss += x[j]*x[j];
  ss = wredsum(ss);
  float n2 = fmaxf(sqrtf(ss), EPSN);
  bool upd = (cnt >= 3.0f);
  #pragma unroll
  for (int j = 0; j < 8; j++) x[j] = upd ? (x[j]/n2) : raw[j];
  ss = 0.f;
  #pragma unroll
  for (int j = 0; j < 8; j++) ss += x[j]*x[j];
  ss = wredsum(ss);
  float n3 = fmaxf(sqrtf(ss), EPSN);
  float dp = 0.f;
  #pragma unroll
  for (int j = 0; j < 8; j++) {
    x[j] = x[j] / n3;
    negc_hat[c*512 + lane*8 + j] = x[j];
    hbuf[c*512 + lane*8 + j] = x[j];
    dp += x[j] * ph[j];
  }
  dp = wredsum(dp);
  if (lane == 0) spn[c] = dp;
  __syncthreads();
  float d4[4] = {0.f,0.f,0.f,0.f};
  #pragma unroll
  for (int c2 = 0; c2 < 4; c2++) {
    float d = 0.f;
    #pragma unroll
    for (int j = 0; j < 8; j++) d += x[j] * hbuf[c2*512 + lane*8 + j];
    d4[c2] = wredsum(d);
  }
  if (lane == 0) {
    #pragma unroll
    for (int c2 = 0; c2 < 4; c2++) snn[c*4 + c2] = d4[c2];
  }
  __syncthreads();
  if (tid == 0) {
    float rep_np = 0.f;
    for (int i = 0; i < 4; i++) rep_np += logf(fmaxf(1.f - spn[i], 1e-6f));
    rep_np = -rep_np * 0.25f;
    float rep_nn = 0.f;
    for (int i = 0; i < 4; i++)
      for (int j2 = 0; j2 < 4; j2++)
        if (i != j2) rep_nn += logf(fmaxf(1.f - snn[i*4+j2], 1e-6f));
    rep_nn = -rep_nn / 12.f;
    scal[4] = rep_np + 0.1f * rep_nn;
  }
}

// ---------------- FUSED: blocks 0..1023 = nloss; 1024..3071 = upass; 32 rows/block each
__global__ __launch_bounds__(256) void k_nlup(const float* __restrict__ NF, const float* __restrict__ inv_n,
                                              const float* __restrict__ nch, float* __restrict__ NlossP,
                                              const float* __restrict__ U, float* __restrict__ SU,
                                              float* __restrict__ UPp, unsigned short* __restrict__ Uh,
                                              float* __restrict__ invU) {
  __shared__ float sh[16];
  int tid = threadIdx.x, lane = tid & 63, w = tid >> 6;
  float nh[4][8];
  #pragma unroll
  for (int c = 0; c < 4; c++)
    #pragma unroll
    for (int j = 0; j < 8; j++) nh[c][j] = nch[c*512 + lane*8 + j];
  if (blockIdx.x < 1024) {
    // ---- nloss path
    float lsum = 0.f;
    int row0 = blockIdx.x * 32;
    for (int rr = w; rr < 32; rr += 4) {
      int row = row0 + rr;
      const float* src = NF + (size_t)row * 512 + lane * 8;
      float4 a = *(const float4*)src;
      float4 b = *(const float4*)(src + 4);
      float x[8] = {a.x,a.y,a.z,a.w,b.x,b.y,b.z,b.w};
      float dn[4] = {0.f,0.f,0.f,0.f};
      #pragma unroll
      for (int j = 0; j < 8; j++)
        #pragma unroll
        for (int c = 0; c < 4; c++) dn[c] += x[j]*nh[c][j];
      #pragma unroll
      for (int c = 0; c < 4; c++) dn[c] = wredsum(dn[c]);
      if (lane == 0) {
        float inv = inv_n[row];
        float s0 = dn[0]*inv, s1 = dn[1]*inv, s2 = dn[2]*inv, s3 = dn[3]*inv;
        float mx = fmaxf(fmaxf(s0,s1), fmaxf(s2,s3));
        float e0 = __expf(s0-mx), e1 = __expf(s1-mx), e2 = __expf(s2-mx), e3 = __expf(s3-mx);
        float Z = e0+e1+e2+e3;
        lsum += (mx + logf(Z)) - (e0*s0+e1*s1+e2*s2+e3*s3)/Z;
      }
    }
    if (lane == 0) sh[w] = lsum;
    __syncthreads();
    if (tid == 0) NlossP[blockIdx.x] = sh[0]+sh[1]+sh[2]+sh[3];
    return;
  }
  // ---- upass path
  const int ub = blockIdx.x - 1024;
  float eacc[4] = {0.f,0.f,0.f,0.f};
  int row0 = ub * 32;
  for (int rr = w; rr < 32; rr += 4) {
    int row = row0 + rr;
    const float* src = U + (size_t)row * 512 + lane * 8;
    float4 a = *(const float4*)src;
    float4 b = *(const float4*)(src + 4);
    float x[8] = {a.x,a.y,a.z,a.w,b.x,b.y,b.z,b.w};
    float ss = 0.f, dn[4] = {0.f,0.f,0.f,0.f};
    #pragma unroll
    for (int j = 0; j < 8; j++) {
      ss += x[j]*x[j];
      #pragma unroll
      for (int c = 0; c < 4; c++) dn[c] += x[j]*nh[c][j];
    }
    ss = wredsum(ss);
    #pragma unroll
    for (int c = 0; c < 4; c++) dn[c] = wredsum(dn[c]);
    float inv = 1.f / fmaxf(sqrtf(ss), EPSN);
    ushort8 o;
    #pragma unroll
    for (int j = 0; j < 8; j++) o[j] = f2bf(x[j]);   // RAW cast; normalized in GEMM epilogue
    *(ushort8*)(Uh + (size_t)row * 512 + lane * 8) = o;
    if (lane == 0) {
      invU[row] = inv;
      float4 sv; sv.x = dn[0]*inv; sv.y = dn[1]*inv; sv.z = dn[2]*inv; sv.w = dn[3]*inv;
      *(float4*)(SU + (size_t)row * 4) = sv;
      eacc[0] += __expf(20.f*sv.x); eacc[1] += __expf(20.f*sv.y);
      eacc[2] += __expf(20.f*sv.z); eacc[3] += __expf(20.f*sv.w);
    }
  }
  if (lane == 0) {
    #pragma unroll
    for (int c = 0; c < 4; c++) sh[w*4+c] = eacc[c];
  }
  __syncthreads();
  if (tid < 4) UPp[ub * 4 + tid] = sh[tid] + sh[4+tid] + sh[8+tid] + sh[12+tid];
}

// ---------------- pseudo sinkhorn pass over [65536][4] f32; Rin = sum of Pin[n_in][4] partials
__global__ __launch_bounds__(256) void k_psink(const float* __restrict__ SU, const float* __restrict__ Pin,
                                               int n_in, float* __restrict__ Pout,
                                               float* __restrict__ PLout, int mode) {
  __shared__ float lr[16];
  int tid = threadIdx.x, lane = tid & 63, w = tid >> 6;
  float i0 = 0.f, i1 = 0.f, i2 = 0.f, i3 = 0.f;
  for (int r = tid; r < n_in; r += 256) {
    float4 v = *(const float4*)(Pin + (size_t)r * 4);
    i0 += v.x; i1 += v.y; i2 += v.z; i3 += v.w;
  }
  i0 = wredsum(i0); i1 = wredsum(i1); i2 = wredsum(i2); i3 = wredsum(i3);
  if (lane == 0) { lr[w*4+0] = i0; lr[w*4+1] = i1; lr[w*4+2] = i2; lr[w*4+3] = i3; }
  __syncthreads();
  float R0 = lr[0]+lr[4]+lr[8]+lr[12];
  float R1_ = lr[1]+lr[5]+lr[9]+lr[13];
  float R2_ = lr[2]+lr[6]+lr[10]+lr[14];
  float R3_ = lr[3]+lr[7]+lr[11]+lr[15];
  float r0 = 1.f/(4.f*R0), r1 = 1.f/(4.f*R1_), r2 = 1.f/(4.f*R2_), r3 = 1.f/(4.f*R3_);
  float a0 = 0.f, a1 = 0.f, a2 = 0.f, a3 = 0.f, lsum = 0.f;
  int row = blockIdx.x * blockDim.x + threadIdx.x;
  {
    float4 s = *(const float4*)(SU + (size_t)row * 4);
    float x0 = __expf(20.f*s.x), x1 = __expf(20.f*s.y);
    float x2 = __expf(20.f*s.z), x3 = __expf(20.f*s.w);
    float E0 = x0*r0, E1 = x1*r1, E2 = x2*r2, E3 = x3*r3;
    float cf = 1.f / ((E0+E1+E2+E3) * 65536.f);
    if (mode == 1) { a0 = x0*cf; a1 = x1*cf; a2 = x2*cf; a3 = x3*cf; }
    else {
      float term = (E0*s.x + E1*s.y + E2*s.z + E3*s.w) * 65536.f * cf;
      float mx = fmaxf(fmaxf(s.x,s.y), fmaxf(s.z,s.w));
      float z = __expf(s.x-mx)+__expf(s.y-mx)+__expf(s.z-mx)+__expf(s.w-mx);
      lsum = (mx + logf(z)) - term;
    }
  }
  __syncthreads();
  if (mode == 1) {
    a0 = wredsum(a0); a1 = wredsum(a1); a2 = wredsum(a2); a3 = wredsum(a3);
    if (lane == 0) { lr[w*4+0] = a0; lr[w*4+1] = a1; lr[w*4+2] = a2; lr[w*4+3] = a3; }
    __syncthreads();
    if (tid < 4) Pout[blockIdx.x * 4 + tid] = lr[tid] + lr[4+tid] + lr[8+tid] + lr[12+tid];
  } else {
    lsum = wredsum(lsum);
    if (lane == 0) lr[w] = lsum;
    __syncthreads();
    if (tid == 0) PLout[blockIdx.x] = lr[0]+lr[1]+lr[2]+lr[3];
  }
}

// ---------------- bf16 GEMM: 256x128 tile, 8 waves (512 thr), XCD-swizzled, XOR-swizzled LDS
// (round-8 version: BK=64 single-buffer; proven 120us / MfmaUtil 23.6% / VGPR=64 occupancy sweet spot)
__global__ __launch_bounds__(512) void k_gemm(const unsigned short* __restrict__ A,
                                              const unsigned short* __restrict__ B,
                                              const float* __restrict__ invU,
                                              const float* __restrict__ invP,
                                              unsigned short* __restrict__ S,
                                              float* __restrict__ R1) {
  __shared__ unsigned short lAB[24576]; // A[256][64](16384) + B[128][64](8192); reused as C[128][136]
  __shared__ float red[1024];
  unsigned short* lA = lAB;
  unsigned short* lB = lAB + 16384;
  const int swz = (blockIdx.x & 7) * 256 + (blockIdx.x >> 3);
  const int rowblk = swz >> 3, colblk = swz & 7;
  const int tid = threadIdx.x, lane = tid & 63;
  const int wid = tid >> 6, wm = wid >> 1, wn = wid & 1;
  f32x4 acc[4][4];
  #pragma unroll
  for (int m = 0; m < 4; m++)
    #pragma unroll
    for (int n = 0; n < 4; n++) acc[m][n] = (f32x4){0.f,0.f,0.f,0.f};
  const unsigned short* Ag = A + (size_t)rowblk * 256 * GK;
  const unsigned short* Bg = B + (size_t)colblk * 128 * GK;
  const int r0 = tid >> 3;
  const int c0 = ((tid & 7) ^ (r0 & 7)) * 8;
  for (int kt = 0; kt < GK; kt += 64) {
    #pragma unroll
    for (int i = 0; i < 4; i++)
      GLL(Ag + (size_t)(r0 + i*64) * GK + kt + c0, lA + (i*512 + tid) * 8);
    #pragma unroll
    for (int i = 0; i < 2; i++)
      GLL(Bg + (size_t)(r0 + i*64) * GK + kt + c0, lB + (i*512 + tid) * 8);
    __syncthreads();
    #pragma unroll
    for (int kk = 0; kk < 2; kk++) {
      short8 af[4], bf[4];
      #pragma unroll
      for (int m = 0; m < 4; m++) {
        int rowA = wm*64 + m*16 + (lane & 15);
        int ch = ((kk*4 + (lane >> 4)) ^ (rowA & 7)) * 8;
        af[m] = *(const short8*)(lA + rowA * 64 + ch);
      }
      #pragma unroll
      for (int n = 0; n < 4; n++) {
        int rowB = wn*64 + n*16 + (lane & 15);
        int ch = ((kk*4 + (lane >> 4)) ^ (rowB & 7)) * 8;
        bf[n] = *(const short8*)(lB + rowB * 64 + ch);
      }
      #pragma unroll
      for (int m = 0; m < 4; m++)
        #pragma unroll
        for (int n = 0; n < 4; n++)
          acc[m][n] = __builtin_amdgcn_mfma_f32_16x16x32_bf16(af[m], bf[n], acc[m][n], 0, 0, 0);
    }
    __syncthreads();
  }
  unsigned short* lC = lAB;
  float racc[16];
  #pragma unroll
  for (int j = 0; j < 16; j++) racc[j] = 0.f;
  const size_t outbase = (size_t)rowblk * 256 * GN + (size_t)colblk * 128;
  const int ch8 = lane & 7, rsub = lane >> 3;
  #pragma unroll
  for (int h = 0; h < 2; h++) {
    if ((wm >> 1) == h) {
      #pragma unroll
      for (int m = 0; m < 4; m++)
        #pragma unroll
        for (int n = 0; n < 4; n++) {
          int col = wn*64 + n*16 + (lane & 15);
          float ip = invP[colblk * 128 + col];
          #pragma unroll
          for (int r = 0; r < 4; r++) {
            int lr2 = (wm & 1)*64 + m*16 + ((lane >> 4) << 2) + r;
            float iu = invU[rowblk * 256 + h*128 + lr2];
            lC[lr2 * 136 + col] = f2bf(acc[m][n][r] * iu * ip);
          }
        }
    }
    __syncthreads();
    #pragma unroll
    for (int it = 0; it < 2; it++) {
      int lr2 = it*64 + wid*8 + rsub;
      int grow = h*128 + lr2;
      ushort8 v0 = *(const ushort8*)(lC + lr2 * 136 + ch8 * 8);
      ushort8 v1 = *(const ushort8*)(lC + lr2 * 136 + 64 + ch8 * 8);
      *(short8*)(S + outbase + (size_t)grow * GN + ch8 * 8) = (short8)v0;
      *(short8*)(S + outbase + (size_t)grow * GN + 64 + ch8 * 8) = (short8)v1;
      #pragma unroll
      for (int j = 0; j < 8; j++) {
        racc[j]     += __expf(20.f * bf2f(v0[j]));
        racc[8 + j] += __expf(20.f * bf2f(v1[j]));
      }
    }
    __syncthreads();
  }
  #pragma unroll
  for (int j = 0; j < 16; j++) {
    racc[j] += __shfl_xor(racc[j], 8);
    racc[j] += __shfl_xor(racc[j], 16);
    racc[j] += __shfl_xor(racc[j], 32);
  }
  if (lane < 8) {
    #pragma unroll
    for (int j = 0; j < 8; j++) {
      red[wid * 128 + lane * 8 + j]      = racc[j];
      red[wid * 128 + 64 + lane * 8 + j] = racc[8 + j];
    }
  }
  __syncthreads();
  if (tid < 128) {
    float s8 = 0.f;
    #pragma unroll
    for (int i = 0; i < 8; i++) s8 += red[i * 128 + tid];
    int gcol = colblk * 128 + tid;
    int q = (gcol & 15) * 64 + (gcol >> 4);
    atomicAdd(&R1[q], s8);
  }
}

// ---------------- sinkhorn col-pass over sim bf16 [65536][1024]; 2-row ILP; 32 rows/block
__global__ __launch_bounds__(256) void k_sink1(const unsigned short* __restrict__ S,
                                               const float* __restrict__ Rin,
                                               float* __restrict__ Pout) {
  __shared__ float lds[4096];
  int tid = threadIdx.x, lane = tid & 63, w = tid >> 6;
  float rj[16];
  #pragma unroll
  for (int j = 0; j < 16; j++) rj[j] = 1.f / (1024.f * Rin[j*64 + lane]);
  float acc[16];
  #pragma unroll
  for (int j = 0; j < 16; j++) acc[j] = 0.f;
  int row0 = blockIdx.x * 32;
  for (int rr = w; rr < 16; rr += 4) {
    const unsigned short* SrA = S + (size_t)(row0 + rr) * 1024 + lane * 16;
    const unsigned short* SrB = S + (size_t)(row0 + rr + 16) * 1024 + lane * 16;
    ushort8 a0 = *(const ushort8*)SrA, a1 = *(const ushort8*)(SrA + 8);
    ushort8 b0 = *(const ushort8*)SrB, b1 = *(const ushort8*)(SrB + 8);
    float XA[16], XB[16];
    float csA = 0.f, csB = 0.f;
    #pragma unroll
    for (int j = 0; j < 8; j++) {
      XA[j]   = __expf(20.f * bf2f(a0[j]));
      XA[8+j] = __expf(20.f * bf2f(a1[j]));
      XB[j]   = __expf(20.f * bf2f(b0[j]));
      XB[8+j] = __expf(20.f * bf2f(b1[j]));
    }
    #pragma unroll
    for (int j = 0; j < 16; j++) { csA += XA[j]*rj[j]; csB += XB[j]*rj[j]; }
    #pragma unroll
    for (int d = 32; d >= 1; d >>= 1) {
      csA += __shfl_xor(csA, d);
      csB += __shfl_xor(csB, d);
    }
    float cfA = 1.f / (csA * 65536.f), cfB = 1.f / (csB * 65536.f);
    #pragma unroll
    for (int j = 0; j < 16; j++) acc[j] += XA[j]*cfA + XB[j]*cfB;
  }
  #pragma unroll
  for (int j = 0; j < 16; j++) lds[w*1024 + lane + 64*j] = acc[j];
  __syncthreads();
  for (int q = tid; q < 1024; q += 256)
    Pout[(size_t)blockIdx.x * 1024 + q] = lds[q] + lds[1024+q] + lds[2048+q] + lds[3072+q];
}

// ---------------- sinkhorn loss pass; 2-row ILP; lse(10s)=log(sum exp(10s)) (10s<=~10.2, safe)
__global__ __launch_bounds__(256) void k_sinkL(const unsigned short* __restrict__ S,
                                               const float* __restrict__ Rin,
                                               float* __restrict__ LPout) {
  __shared__ float lr[4];
  int tid = threadIdx.x, lane = tid & 63, w = tid >> 6;
  float rj[16];
  #pragma unroll
  for (int j = 0; j < 16; j++) rj[j] = 1.f / (1024.f * Rin[j*64 + lane]);
  float lsum = 0.f;
  int row0 = blockIdx.x * 32;
  for (int rr = w; rr < 16; rr += 4) {
    const unsigned short* SrA = S + (size_t)(row0 + rr) * 1024 + lane * 16;
    const unsigned short* SrB = S + (size_t)(row0 + rr + 16) * 1024 + lane * 16;
    ushort8 a0 = *(const ushort8*)SrA, a1 = *(const ushort8*)(SrA + 8);
    ushort8 b0 = *(const ushort8*)SrB, b1 = *(const ushort8*)(SrB + 8);
    float sA[16], sB[16], yA[16], yB[16];
    #pragma unroll
    for (int j = 0; j < 8; j++) {
      sA[j] = bf2f(a0[j]); sA[8+j] = bf2f(a1[j]);
      sB[j] = bf2f(b0[j]); sB[8+j] = bf2f(b1[j]);
    }
    #pragma unroll
    for (int j = 0; j < 16; j++) { yA[j] = __expf(10.f*sA[j]); yB[j] = __expf(10.f*sB[j]); }
    float csA = 0.f, csB = 0.f, tA = 0.f, tB = 0.f, YA = 0.f, YB = 0.f;
    #pragma unroll
    for (int j = 0; j < 16; j++) {
      float xa = yA[j]*yA[j]*rj[j];
      float xb = yB[j]*yB[j]*rj[j];
      csA += xa; tA += xa*sA[j]; YA += yA[j];
      csB += xb; tB += xb*sB[j]; YB += yB[j];
    }
    #pragma unroll
    for (int d = 32; d >= 1; d >>= 1) {
      csA += __shfl_xor(csA, d); csB += __shfl_xor(csB, d);
      tA  += __shfl_xor(tA, d);  tB  += __shfl_xor(tB, d);
      YA  += __shfl_xor(YA, d);  YB  += __shfl_xor(YB, d);
    }
    if (lane == 0)
      lsum += (logf(YA) - 10.f*tA/csA) + (logf(YB) - 10.f*tB/csB);
  }
  if (lane == 0) lr[w] = lsum;
  __syncthreads();
  if (tid == 0) LPout[blockIdx.x] = lr[0]+lr[1]+lr[2]+lr[3];
}

// ---------------- finalize: sum all loss partials, write 5 f32 outputs
__global__ __launch_bounds__(256) void k_final(const float* __restrict__ scal,
                                               const float* __restrict__ PlossP,
                                               const float* __restrict__ NlossP,
                                               const float* __restrict__ PLp,
                                               const float* __restrict__ SLp,
                                               float* __restrict__ out) {
  __shared__ float lr[4];
  int tid = threadIdx.x, lane = tid & 63, w = tid >> 6;
  float tots[4];
  const float* arrs[4] = {PlossP, NlossP, PLp, SLp};
  const int ns[4] = {512, 1024, 256, 2048};
  for (int k = 0; k < 4; k++) {
    float s = 0.f;
    for (int i = tid; i < ns[k]; i += 256) s += arrs[k][i];
    s = wredsum(s);
    __syncthreads();
    if (lane == 0) lr[w] = s;
    __syncthreads();
    tots[k] = lr[0]+lr[1]+lr[2]+lr[3];
  }
  if (tid == 0) {
    float l   = 1.f - tots[0] / 16384.f;
    float ln  = tots[1] / 32768.f;
    float lp  = tots[2] / 65536.f;
    float ul  = tots[3] / 65536.f;
    float rep = scal[4];
    float nl  = 0.5f * (ln + lp);
    float cls = 0.45f*l + 0.3f*nl + 0.1f*ul + 0.15f*rep;
    out[0] = cls;
    out[1] = l;
    out[2] = ul;
    out[3] = nl;
    out[4] = rep;
  }
}

extern "C" void kernel_launch(void* const* d_in, const int* in_sizes, int n_in,
                              void* d_out, int out_size, void* d_ws, size_t ws_size,
                              hipStream_t stream) {
  const float* PF = (const float*)d_in[0];   // p_feats [16384][512]
  const float* UF = (const float*)d_in[1];   // u_feats [65536][512]
  const float* NF = (const float*)d_in[2];   // n_feats [32768][512]
  const float* PC = (const float*)d_in[3];   // positive_center [1][512]
  const float* PU = (const float*)d_in[4];   // proxy_u [1024][512]
  const float* NC = (const float*)d_in[5];   // negative_centers [4][512]

  char* ws = (char*)d_ws;
  const size_t WS_REQUIRED = 202736768ULL;
  if (ws_size < WS_REQUIRED) return;

  float* R1     = (float*)(ws + 0);        // 1024 f32, q-order (zeroed; gemm atomics)
  float* R2     = (float*)(ws + 4096);     // 1024 f32, q-order
  float* R3     = (float*)(ws + 8192);     // 1024 f32, q-order
  float* scal   = (float*)(ws + 12288);    // 16 f32; only [4]=repulsion used
  float* sums   = (float*)(ws + 12416);    // 2048 f32
  float* invP   = (float*)(ws + 20608);    // 1024 f32
  float* UPp    = (float*)(ws + 24704);    // [2048][4]
  float* PPpA   = (float*)(ws + 57472);    // [256][4]
  float* PPpB   = (float*)(ws + 61568);    // [256][4]
  float* PLp    = (float*)(ws + 65664);    // [256]
  float* PlossP = (float*)(ws + 66688);    // [512]
  float* NlossP = (float*)(ws + 68736);    // [1024]
  float* pos_hat   = (float*)(ws + 81024); // 512 f32
  float* negc0_hat = (float*)(ws + 83072); // 2048 f32
  float* negc_hat  = (float*)(ws + 91264); // 2048 f32
  float* invU      = (float*)(ws + 99456); // 65536 f32
  float* SU    = (float*)(ws + 361600);            // [65536][4] f32 (nlup -> psink)
  unsigned short* Ph = (unsigned short*)(ws + 361600); // [1024][512] bf16 (after psink; aliases SU)
  float* SumP = (float*)(ws + 1410176);            // [1024][2048] f32 (8 MB; plns -> redcol)
  unsigned short* Uh = (unsigned short*)(ws + 1410176); // [65536][512] bf16 (nlup -> gemm; after redcol)
  float* SPp  = (float*)(ws + 1410176);            // [2048][1024] f32 (after gemm)
  float* SLp  = (float*)(ws + 9798784);            // [2048] f32 (sinkL; after gemm, Uh dead)
  float* CntP = (float*)(ws + 9806976);            // [1024][4] f32 (plns -> center; before Uh written)
  unsigned short* S = (unsigned short*)(ws + 68519040); // [65536][1024] bf16 (gemm output)
  float* inv_n = (float*)(ws + 68519040);          // 32768 f32 — inside S region; dead before gemm writes S

  hipMemsetAsync(ws, 0, 4096, stream);  // only R1 needs zeroing (gemm atomics)

  k_prep<<<1, 320, 0, stream>>>(PC, NC, pos_hat, negc0_hat);
  k_plns<<<1536, 256, 0, stream>>>(PF, pos_hat, PlossP, NF, negc0_hat, inv_n, CntP, SumP);
  k_redcol<<<128, 256, 0, stream>>>(SumP, sums, 1024, 2048);
  k_center<<<1, 256, 0, stream>>>(CntP, sums, NC, pos_hat, negc_hat, scal);
  k_nlup<<<3072, 256, 0, stream>>>(NF, inv_n, negc_hat, NlossP, UF, SU, UPp, Uh, invU);

  // pseudo sinkhorn (K=4), partial-in partial-out
  k_psink<<<256, 256, 0, stream>>>(SU, UPp, 2048, PPpA, nullptr, 1);
  k_psink<<<256, 256, 0, stream>>>(SU, PPpA, 256, PPpB, nullptr, 1);
  k_psink<<<256, 256, 0, stream>>>(SU, PPpB, 256, nullptr, PLp, 2);

  k_rownormP<<<32, 256, 0, stream>>>(PU, Ph, invP, 1024);  // Ph overlaps dead SU

  // u branch: GEMM + 3 sinkhorn passes with partial-based column reduction
  k_gemm<<<2048, 512, 0, stream>>>(Uh, Ph, invU, invP, S, R1);
  k_sink1<<<2048, 256, 0, stream>>>(S, R1, SPp);
  k_redcol<<<64, 256, 0, stream>>>(SPp, R2, 2048, 1024);
  k_sink1<<<2048, 256, 0, stream>>>(S, R2, SPp);
  k_redcol<<<64, 256, 0, stream>>>(SPp, R3, 2048, 1024);
  k_sinkL<<<2048, 256, 0, stream>>>(S, R3, SLp);

  k_final<<<1, 256, 0, stream>>>(scal, PlossP, NlossP, PLp, SLp, (float*)d_out);
}

// Round 13
// 401.023 us; speedup vs baseline: 1.0500x; 1.0277x over previous
//
#include <hip/hip_runtime.h>
#include <hip/hip_bf16.h>
#include <hip/hip_fp16.h>

typedef __attribute__((ext_vector_type(8))) short short8;
typedef __attribute__((ext_vector_type(8))) unsigned short ushort8;
typedef __attribute__((ext_vector_type(8))) unsigned char uchar8;
typedef __attribute__((ext_vector_type(16))) unsigned char uchar16;
typedef __attribute__((ext_vector_type(4))) float f32x4;

#define EPSN 1e-12f
#define GN 1024
#define GK 512

__device__ __forceinline__ float bf2f(unsigned short h) {
  union { unsigned int u; float f; } c; c.u = ((unsigned int)h) << 16; return c.f;
}
__device__ __forceinline__ unsigned short f2bf(float f) {
  union { float f; unsigned int u; } c; c.f = f;
  unsigned int u = c.u;
  return (unsigned short)((u + 0x7fffu + ((u >> 16) & 1u)) >> 16);
}
// e5m2 fp8 = top byte of fp16, round-to-nearest-even. |s|<=1.2 -> no overflow/NaN path.
__device__ __forceinline__ unsigned char f2e5(float f) {
  unsigned short u = __half_as_ushort(__float2half(f));
  return (unsigned char)((u + 0x7Fu + ((u >> 8) & 1u)) >> 8);
}
__device__ __forceinline__ float e52f(unsigned char c) {
  return __half2float(__ushort_as_half((unsigned short)(((unsigned short)c) << 8)));
}
__device__ __forceinline__ float wredsum(float v) {
  v += __shfl_xor(v, 32); v += __shfl_xor(v, 16); v += __shfl_xor(v, 8);
  v += __shfl_xor(v, 4);  v += __shfl_xor(v, 2);  v += __shfl_xor(v, 1);
  return v;
}

#define GLL(g, l) __builtin_amdgcn_global_load_lds( \
    (const __attribute__((address_space(1))) unsigned int*)(g), \
    (__attribute__((address_space(3))) unsigned int*)(l), 16, 0, 0)

// ---------------- prep: normalize positive_center (1 row) + negative_centers (4 rows)
__global__ void k_prep(const float* __restrict__ pc, const float* __restrict__ nc,
                       float* __restrict__ pos_hat, float* __restrict__ negc0_hat) {
  int tid = threadIdx.x, lane = tid & 63, w = tid >> 6; // 5 waves
  const float* src = (w == 0) ? pc : (nc + (w - 1) * 512);
  float* dst = (w == 0) ? pos_hat : (negc0_hat + (w - 1) * 512);
  float4 a = *(const float4*)(src + lane * 8);
  float4 b = *(const float4*)(src + lane * 8 + 4);
  float x[8] = {a.x,a.y,a.z,a.w,b.x,b.y,b.z,b.w};
  float ss = 0.f;
  #pragma unroll
  for (int j = 0; j < 8; j++) ss += x[j]*x[j];
  ss = wredsum(ss);
  float inv = 1.f / fmaxf(sqrtf(ss), EPSN);
  #pragma unroll
  for (int j = 0; j < 8; j++) dst[lane*8+j] = x[j]*inv;
}

// ---------------- generic column reduce: R[col] = sum_r P[r][col]; grid = ncols/16
__global__ __launch_bounds__(256) void k_redcol(const float* __restrict__ P, float* __restrict__ R,
                                                int nrows, int ncols) {
  __shared__ float lred[64];
  int tid = threadIdx.x, lane = tid & 63, w = tid >> 6;
  int colg = blockIdx.x * 16;
  int ci = tid & 15;
  int r0 = tid >> 4; // 0..15
  float s = 0.f;
  for (int r = r0; r < nrows; r += 16)
    s += P[(size_t)r * ncols + colg + ci];
  s += __shfl_xor(s, 16); s += __shfl_xor(s, 32);
  if (lane < 16) lred[w * 16 + lane] = s;
  __syncthreads();
  if (tid < 16) R[colg + tid] = lred[tid] + lred[16 + tid] + lred[32 + tid] + lred[48 + tid];
}

// ---------------- row norms for proxy: RAW bf16 cast + 1/||row||
__global__ __launch_bounds__(256) void k_rownormP(const float* __restrict__ X,
                                                  unsigned short* __restrict__ Y,
                                                  float* __restrict__ invn, int rows) {
  int lane = threadIdx.x & 63;
  int w0 = blockIdx.x * 4 + (threadIdx.x >> 6);
  int nw = gridDim.x * 4;
  for (int row = w0; row < rows; row += nw) {
    const float* src = X + (size_t)row * 512 + lane * 8;
    float4 a = *(const float4*)src;
    float4 b = *(const float4*)(src + 4);
    float x[8] = {a.x,a.y,a.z,a.w,b.x,b.y,b.z,b.w};
    float ss = 0.f;
    #pragma unroll
    for (int j = 0; j < 8; j++) ss += x[j]*x[j];
    ss = wredsum(ss);
    float inv = 1.f / fmaxf(sqrtf(ss), EPSN);
    if (lane == 0) invn[row] = inv;
    ushort8 o;
    #pragma unroll
    for (int j = 0; j < 8; j++) o[j] = f2bf(x[j]);
    *(ushort8*)(Y + (size_t)row * 512 + lane * 8) = o;
  }
}

// ---------------- FUSED: blocks 0..511 = ploss partials; 512..1535 = nstats; 32 rows/block each
__global__ __launch_bounds__(256) void k_plns(const float* __restrict__ PF, const float* __restrict__ ph_g,
                                              float* __restrict__ PlossP,
                                              const float* __restrict__ NF, const float* __restrict__ nch0,
                                              float* __restrict__ inv_n, float* __restrict__ CntP,
                                              float* __restrict__ SumP) {
  __shared__ float fl[8192]; // nstats: [4 waves][4][512]
  __shared__ float cb[16];
  int tid = threadIdx.x, lane = tid & 63, w = tid >> 6;
  if (blockIdx.x < 512) {
    // ---- ploss path
    float ph[8];
    #pragma unroll
    for (int j = 0; j < 8; j++) ph[j] = ph_g[lane*8+j];
    float lsum = 0.f;
    int row0 = blockIdx.x * 32;
    for (int rr = w; rr < 32; rr += 4) {
      int row = row0 + rr;
      const float* src = PF + (size_t)row * 512 + lane * 8;
      float4 a = *(const float4*)src;
      float4 b = *(const float4*)(src + 4);
      float x[8] = {a.x,a.y,a.z,a.w,b.x,b.y,b.z,b.w};
      float ss = 0.f, dp = 0.f;
      #pragma unroll
      for (int j = 0; j < 8; j++) { ss += x[j]*x[j]; dp += x[j]*ph[j]; }
      ss = wredsum(ss); dp = wredsum(dp);
      if (lane == 0) lsum += dp / fmaxf(sqrtf(ss), EPSN);
    }
    if (lane == 0) cb[w] = lsum;
    __syncthreads();
    if (tid == 0) PlossP[blockIdx.x] = cb[0]+cb[1]+cb[2]+cb[3];
    return;
  }
  // ---- nstats path
  const int nb = blockIdx.x - 512;
  float ph[8], nh[4][8];
  #pragma unroll
  for (int j = 0; j < 8; j++) ph[j] = ph_g[lane*8+j];
  #pragma unroll
  for (int c = 0; c < 4; c++)
    #pragma unroll
    for (int j = 0; j < 8; j++) nh[c][j] = nch0[c*512 + lane*8 + j];
  float acc[4][8];
  float cnt[4] = {0.f,0.f,0.f,0.f};
  #pragma unroll
  for (int c = 0; c < 4; c++)
    #pragma unroll
    for (int j = 0; j < 8; j++) acc[c][j] = 0.f;
  int row0 = nb * 32;
  for (int rr = w; rr < 32; rr += 4) {
    int row = row0 + rr;
    const float* src = NF + (size_t)row * 512 + lane * 8;
    float4 a = *(const float4*)src;
    float4 b = *(const float4*)(src + 4);
    float x[8] = {a.x,a.y,a.z,a.w,b.x,b.y,b.z,b.w};
    float ss = 0.f, dp = 0.f, dn[4] = {0.f,0.f,0.f,0.f};
    #pragma unroll
    for (int j = 0; j < 8; j++) {
      ss += x[j]*x[j]; dp += x[j]*ph[j];
      #pragma unroll
      for (int c = 0; c < 4; c++) dn[c] += x[j]*nh[c][j];
    }
    ss = wredsum(ss); dp = wredsum(dp);
    #pragma unroll
    for (int c = 0; c < 4; c++) dn[c] = wredsum(dn[c]);
    float inv = 1.f / fmaxf(sqrtf(ss), EPSN);
    if (lane == 0) inv_n[row] = inv;
    float sp = dp * inv;
    float s0 = dn[0]*inv, s1 = dn[1]*inv, s2 = dn[2]*inv, s3 = dn[3]*inv;
    int am = 0; float best = s0;
    if (s1 > best) { best = s1; am = 1; }
    if (s2 > best) { best = s2; am = 2; }
    if (s3 > best) { best = s3; am = 3; }
    float kf = (sp < 0.7f) ? 1.f : 0.f;
    #pragma unroll
    for (int c = 0; c < 4; c++) {
      float m = (am == c) ? kf : 0.f;
      #pragma unroll
      for (int j = 0; j < 8; j++) acc[c][j] += m * x[j];
      if (lane == 0) cnt[c] += m;
    }
  }
  #pragma unroll
  for (int c = 0; c < 4; c++)
    #pragma unroll
    for (int j = 0; j < 8; j++) fl[w*2048 + c*512 + lane*8 + j] = acc[c][j];
  if (lane == 0) {
    #pragma unroll
    for (int c = 0; c < 4; c++) cb[w*4+c] = cnt[c];
  }
  __syncthreads();
  for (int q = tid; q < 2048; q += 256)
    SumP[(size_t)nb * 2048 + q] = fl[q] + fl[2048+q] + fl[4096+q] + fl[6144+q];
  if (tid < 4) CntP[nb * 4 + tid] = cb[tid] + cb[4+tid] + cb[8+tid] + cb[12+tid];
}

// ---------------- center update + repulsion (single block, wave per cluster)
__global__ void k_center(const float* __restrict__ CntP, const float* __restrict__ sums,
                         const float* __restrict__ negc_raw, const float* __restrict__ pos_hat,
                         float* __restrict__ negc_hat, float* __restrict__ scal) {
  __shared__ float hbuf[2048];
  __shared__ float spn[4];
  __shared__ float snn[16];
  int tid = threadIdx.x, lane = tid & 63, c = tid >> 6;
  float cs = 0.f;
  for (int r = lane; r < 1024; r += 64) cs += CntP[r*4 + c];
  float cnt = wredsum(cs);
  float x[8], raw[8], ph[8];
  #pragma unroll
  for (int j = 0; j < 8; j++) {
    x[j] = sums[c*512 + lane*8 + j] / fmaxf(cnt, 1.f);
    raw[j] = negc_raw[c*512 + lane*8 + j];
    ph[j] = pos_hat[lane*8 + j];
  }
  float ss = 0.f;
  #pragma unroll
  for (int j = 0; j < 8; j++) ss += x[j]*x[j];
  ss = wredsum(ss);
  float n1 = fmaxf(sqrtf(ss), EPSN);
  #pragma unroll
  for (int j = 0; j < 8; j++) x[j] = raw[j] + (x[j]/n1 - raw[j]) * 0.1f;
  ss = 0.f;
  #pragma unroll
  for (int j = 0; j < 8; j++) ss += x[j]*x[j];
  ss = wredsum(ss);
  float n2 = fmaxf(sqrtf(ss), EPSN);
  bool upd = (cnt >= 3.0f);
  #pragma unroll
  for (int j = 0; j < 8; j++) x[j] = upd ? (x[j]/n2) : raw[j];
  ss = 0.f;
  #pragma unroll
  for (int j = 0; j < 8; j++) ss += x[j]*x[j];
  ss = wredsum(ss);
  float n3 = fmaxf(sqrtf(ss), EPSN);
  float dp = 0.f;
  #pragma unroll
  for (int j = 0; j < 8; j++) {
    x[j] = x[j] / n3;
    negc_hat[c*512 + lane*8 + j] = x[j];
    hbuf[c*512 + lane*8 + j] = x[j];
    dp += x[j] * ph[j];
  }
  dp = wredsum(dp);
  if (lane == 0) spn[c] = dp;
  __syncthreads();
  float d4[4] = {0.f,0.f,0.f,0.f};
  #pragma unroll
  for (int c2 = 0; c2 < 4; c2++) {
    float d = 0.f;
    #pragma unroll
    for (int j = 0; j < 8; j++) d += x[j] * hbuf[c2*512 + lane*8 + j];
    d4[c2] = wredsum(d);
  }
  if (lane == 0) {
    #pragma unroll
    for (int c2 = 0; c2 < 4; c2++) snn[c*4 + c2] = d4[c2];
  }
  __syncthreads();
  if (tid == 0) {
    float rep_np = 0.f;
    for (int i = 0; i < 4; i++) rep_np += logf(fmaxf(1.f - spn[i], 1e-6f));
    rep_np = -rep_np * 0.25f;
    float rep_nn = 0.f;
    for (int i = 0; i < 4; i++)
      for (int j2 = 0; j2 < 4; j2++)
        if (i != j2) rep_nn += logf(fmaxf(1.f - snn[i*4+j2], 1e-6f));
    rep_nn = -rep_nn / 12.f;
    scal[4] = rep_np + 0.1f * rep_nn;
  }
}

// ---------------- FUSED: blocks 0..1023 = nloss; 1024..3071 = upass; 32 rows/block each
__global__ __launch_bounds__(256) void k_nlup(const float* __restrict__ NF, const float* __restrict__ inv_n,
                                              const float* __restrict__ nch, float* __restrict__ NlossP,
                                              const float* __restrict__ U, float* __restrict__ SU,
                                              float* __restrict__ UPp, unsigned short* __restrict__ Uh,
                                              float* __restrict__ invU) {
  __shared__ float sh[16];
  int tid = threadIdx.x, lane = tid & 63, w = tid >> 6;
  float nh[4][8];
  #pragma unroll
  for (int c = 0; c < 4; c++)
    #pragma unroll
    for (int j = 0; j < 8; j++) nh[c][j] = nch[c*512 + lane*8 + j];
  if (blockIdx.x < 1024) {
    // ---- nloss path
    float lsum = 0.f;
    int row0 = blockIdx.x * 32;
    for (int rr = w; rr < 32; rr += 4) {
      int row = row0 + rr;
      const float* src = NF + (size_t)row * 512 + lane * 8;
      float4 a = *(const float4*)src;
      float4 b = *(const float4*)(src + 4);
      float x[8] = {a.x,a.y,a.z,a.w,b.x,b.y,b.z,b.w};
      float dn[4] = {0.f,0.f,0.f,0.f};
      #pragma unroll
      for (int j = 0; j < 8; j++)
        #pragma unroll
        for (int c = 0; c < 4; c++) dn[c] += x[j]*nh[c][j];
      #pragma unroll
      for (int c = 0; c < 4; c++) dn[c] = wredsum(dn[c]);
      if (lane == 0) {
        float inv = inv_n[row];
        float s0 = dn[0]*inv, s1 = dn[1]*inv, s2 = dn[2]*inv, s3 = dn[3]*inv;
        float mx = fmaxf(fmaxf(s0,s1), fmaxf(s2,s3));
        float e0 = __expf(s0-mx), e1 = __expf(s1-mx), e2 = __expf(s2-mx), e3 = __expf(s3-mx);
        float Z = e0+e1+e2+e3;
        lsum += (mx + logf(Z)) - (e0*s0+e1*s1+e2*s2+e3*s3)/Z;
      }
    }
    if (lane == 0) sh[w] = lsum;
    __syncthreads();
    if (tid == 0) NlossP[blockIdx.x] = sh[0]+sh[1]+sh[2]+sh[3];
    return;
  }
  // ---- upass path
  const int ub = blockIdx.x - 1024;
  float eacc[4] = {0.f,0.f,0.f,0.f};
  int row0 = ub * 32;
  for (int rr = w; rr < 32; rr += 4) {
    int row = row0 + rr;
    const float* src = U + (size_t)row * 512 + lane * 8;
    float4 a = *(const float4*)src;
    float4 b = *(const float4*)(src + 4);
    float x[8] = {a.x,a.y,a.z,a.w,b.x,b.y,b.z,b.w};
    float ss = 0.f, dn[4] = {0.f,0.f,0.f,0.f};
    #pragma unroll
    for (int j = 0; j < 8; j++) {
      ss += x[j]*x[j];
      #pragma unroll
      for (int c = 0; c < 4; c++) dn[c] += x[j]*nh[c][j];
    }
    ss = wredsum(ss);
    #pragma unroll
    for (int c = 0; c < 4; c++) dn[c] = wredsum(dn[c]);
    float inv = 1.f / fmaxf(sqrtf(ss), EPSN);
    ushort8 o;
    #pragma unroll
    for (int j = 0; j < 8; j++) o[j] = f2bf(x[j]);   // RAW cast; normalized in GEMM epilogue
    *(ushort8*)(Uh + (size_t)row * 512 + lane * 8) = o;
    if (lane == 0) {
      invU[row] = inv;
      float4 sv; sv.x = dn[0]*inv; sv.y = dn[1]*inv; sv.z = dn[2]*inv; sv.w = dn[3]*inv;
      *(float4*)(SU + (size_t)row * 4) = sv;
      eacc[0] += __expf(20.f*sv.x); eacc[1] += __expf(20.f*sv.y);
      eacc[2] += __expf(20.f*sv.z); eacc[3] += __expf(20.f*sv.w);
    }
  }
  if (lane == 0) {
    #pragma unroll
    for (int c = 0; c < 4; c++) sh[w*4+c] = eacc[c];
  }
  __syncthreads();
  if (tid < 4) UPp[ub * 4 + tid] = sh[tid] + sh[4+tid] + sh[8+tid] + sh[12+tid];
}

// ---------------- pseudo sinkhorn pass over [65536][4] f32; Rin = sum of Pin[n_in][4] partials
__global__ __launch_bounds__(256) void k_psink(const float* __restrict__ SU, const float* __restrict__ Pin,
                                               int n_in, float* __restrict__ Pout,
                                               float* __restrict__ PLout, int mode) {
  __shared__ float lr[16];
  int tid = threadIdx.x, lane = tid & 63, w = tid >> 6;
  float i0 = 0.f, i1 = 0.f, i2 = 0.f, i3 = 0.f;
  for (int r = tid; r < n_in; r += 256) {
    float4 v = *(const float4*)(Pin + (size_t)r * 4);
    i0 += v.x; i1 += v.y; i2 += v.z; i3 += v.w;
  }
  i0 = wredsum(i0); i1 = wredsum(i1); i2 = wredsum(i2); i3 = wredsum(i3);
  if (lane == 0) { lr[w*4+0] = i0; lr[w*4+1] = i1; lr[w*4+2] = i2; lr[w*4+3] = i3; }
  __syncthreads();
  float R0 = lr[0]+lr[4]+lr[8]+lr[12];
  float R1_ = lr[1]+lr[5]+lr[9]+lr[13];
  float R2_ = lr[2]+lr[6]+lr[10]+lr[14];
  float R3_ = lr[3]+lr[7]+lr[11]+lr[15];
  float r0 = 1.f/(4.f*R0), r1 = 1.f/(4.f*R1_), r2 = 1.f/(4.f*R2_), r3 = 1.f/(4.f*R3_);
  float a0 = 0.f, a1 = 0.f, a2 = 0.f, a3 = 0.f, lsum = 0.f;
  int row = blockIdx.x * blockDim.x + threadIdx.x;
  {
    float4 s = *(const float4*)(SU + (size_t)row * 4);
    float x0 = __expf(20.f*s.x), x1 = __expf(20.f*s.y);
    float x2 = __expf(20.f*s.z), x3 = __expf(20.f*s.w);
    float E0 = x0*r0, E1 = x1*r1, E2 = x2*r2, E3 = x3*r3;
    float cf = 1.f / ((E0+E1+E2+E3) * 65536.f);
    if (mode == 1) { a0 = x0*cf; a1 = x1*cf; a2 = x2*cf; a3 = x3*cf; }
    else {
      float term = (E0*s.x + E1*s.y + E2*s.z + E3*s.w) * 65536.f * cf;
      float mx = fmaxf(fmaxf(s.x,s.y), fmaxf(s.z,s.w));
      float z = __expf(s.x-mx)+__expf(s.y-mx)+__expf(s.z-mx)+__expf(s.w-mx);
      lsum = (mx + logf(z)) - term;
    }
  }
  __syncthreads();
  if (mode == 1) {
    a0 = wredsum(a0); a1 = wredsum(a1); a2 = wredsum(a2); a3 = wredsum(a3);
    if (lane == 0) { lr[w*4+0] = a0; lr[w*4+1] = a1; lr[w*4+2] = a2; lr[w*4+3] = a3; }
    __syncthreads();
    if (tid < 4) Pout[blockIdx.x * 4 + tid] = lr[tid] + lr[4+tid] + lr[8+tid] + lr[12+tid];
  } else {
    lsum = wredsum(lsum);
    if (lane == 0) lr[w] = lsum;
    __syncthreads();
    if (tid == 0) PLout[blockIdx.x] = lr[0]+lr[1]+lr[2]+lr[3];
  }
}

// ---------------- bf16 GEMM: 256x128 tile, 8 waves (512 thr), XCD-swizzled, XOR-swizzled LDS
// Epilogue now stores S as fp8 e5m2 (half the write traffic); R1 computed from the
// QUANTIZED values so all downstream sinkhorn algebra is self-consistent.
__global__ __launch_bounds__(512) void k_gemm(const unsigned short* __restrict__ A,
                                              const unsigned short* __restrict__ B,
                                              const float* __restrict__ invU,
                                              const float* __restrict__ invP,
                                              unsigned char* __restrict__ S8,
                                              float* __restrict__ R1) {
  __shared__ unsigned short lAB[24576]; // A[256][64](16384) + B[128][64](8192); reused as C[128][136]
  __shared__ float red[1024];
  unsigned short* lA = lAB;
  unsigned short* lB = lAB + 16384;
  const int swz = (blockIdx.x & 7) * 256 + (blockIdx.x >> 3);
  const int rowblk = swz >> 3, colblk = swz & 7;
  const int tid = threadIdx.x, lane = tid & 63;
  const int wid = tid >> 6, wm = wid >> 1, wn = wid & 1;
  f32x4 acc[4][4];
  #pragma unroll
  for (int m = 0; m < 4; m++)
    #pragma unroll
    for (int n = 0; n < 4; n++) acc[m][n] = (f32x4){0.f,0.f,0.f,0.f};
  const unsigned short* Ag = A + (size_t)rowblk * 256 * GK;
  const unsigned short* Bg = B + (size_t)colblk * 128 * GK;
  const int r0 = tid >> 3;
  const int c0 = ((tid & 7) ^ (r0 & 7)) * 8;
  for (int kt = 0; kt < GK; kt += 64) {
    #pragma unroll
    for (int i = 0; i < 4; i++)
      GLL(Ag + (size_t)(r0 + i*64) * GK + kt + c0, lA + (i*512 + tid) * 8);
    #pragma unroll
    for (int i = 0; i < 2; i++)
      GLL(Bg + (size_t)(r0 + i*64) * GK + kt + c0, lB + (i*512 + tid) * 8);
    __syncthreads();
    #pragma unroll
    for (int kk = 0; kk < 2; kk++) {
      short8 af[4], bf[4];
      #pragma unroll
      for (int m = 0; m < 4; m++) {
        int rowA = wm*64 + m*16 + (lane & 15);
        int ch = ((kk*4 + (lane >> 4)) ^ (rowA & 7)) * 8;
        af[m] = *(const short8*)(lA + rowA * 64 + ch);
      }
      #pragma unroll
      for (int n = 0; n < 4; n++) {
        int rowB = wn*64 + n*16 + (lane & 15);
        int ch = ((kk*4 + (lane >> 4)) ^ (rowB & 7)) * 8;
        bf[n] = *(const short8*)(lB + rowB * 64 + ch);
      }
      #pragma unroll
      for (int m = 0; m < 4; m++)
        #pragma unroll
        for (int n = 0; n < 4; n++)
          acc[m][n] = __builtin_amdgcn_mfma_f32_16x16x32_bf16(af[m], bf[n], acc[m][n], 0, 0, 0);
    }
    __syncthreads();
  }
  unsigned short* lC = lAB;
  float racc[16];
  #pragma unroll
  for (int j = 0; j < 16; j++) racc[j] = 0.f;
  const size_t outbase = (size_t)rowblk * 256 * GN + (size_t)colblk * 128;
  const int ch8 = lane & 7, rsub = lane >> 3;
  #pragma unroll
  for (int h = 0; h < 2; h++) {
    if ((wm >> 1) == h) {
      #pragma unroll
      for (int m = 0; m < 4; m++)
        #pragma unroll
        for (int n = 0; n < 4; n++) {
          int col = wn*64 + n*16 + (lane & 15);
          float ip = invP[colblk * 128 + col];
          #pragma unroll
          for (int r = 0; r < 4; r++) {
            int lr2 = (wm & 1)*64 + m*16 + ((lane >> 4) << 2) + r;
            float iu = invU[rowblk * 256 + h*128 + lr2];
            lC[lr2 * 136 + col] = f2bf(acc[m][n][r] * iu * ip);
          }
        }
    }
    __syncthreads();
    #pragma unroll
    for (int it = 0; it < 2; it++) {
      int lr2 = it*64 + wid*8 + rsub;
      int grow = h*128 + lr2;
      ushort8 v0 = *(const ushort8*)(lC + lr2 * 136 + ch8 * 8);
      ushort8 v1 = *(const ushort8*)(lC + lr2 * 136 + 64 + ch8 * 8);
      uchar8 o0, o1;
      #pragma unroll
      for (int j = 0; j < 8; j++) {
        unsigned char c0v = f2e5(bf2f(v0[j]));
        unsigned char c1v = f2e5(bf2f(v1[j]));
        o0[j] = c0v; o1[j] = c1v;
        racc[j]     += __expf(20.f * e52f(c0v));
        racc[8 + j] += __expf(20.f * e52f(c1v));
      }
      *(uchar8*)(S8 + outbase + (size_t)grow * GN + ch8 * 8) = o0;
      *(uchar8*)(S8 + outbase + (size_t)grow * GN + 64 + ch8 * 8) = o1;
    }
    __syncthreads();
  }
  #pragma unroll
  for (int j = 0; j < 16; j++) {
    racc[j] += __shfl_xor(racc[j], 8);
    racc[j] += __shfl_xor(racc[j], 16);
    racc[j] += __shfl_xor(racc[j], 32);
  }
  if (lane < 8) {
    #pragma unroll
    for (int j = 0; j < 8; j++) {
      red[wid * 128 + lane * 8 + j]      = racc[j];
      red[wid * 128 + 64 + lane * 8 + j] = racc[8 + j];
    }
  }
  __syncthreads();
  if (tid < 128) {
    float s8 = 0.f;
    #pragma unroll
    for (int i = 0; i < 8; i++) s8 += red[i * 128 + tid];
    int gcol = colblk * 128 + tid;
    int q = (gcol & 15) * 64 + (gcol >> 4);
    atomicAdd(&R1[q], s8);
  }
}

// ---------------- sinkhorn col-pass over sim fp8 [65536][1024]; 2-row ILP; 32 rows/block
__global__ __launch_bounds__(256) void k_sink1(const unsigned char* __restrict__ S8,
                                               const float* __restrict__ Rin,
                                               float* __restrict__ Pout) {
  __shared__ float lds[4096];
  int tid = threadIdx.x, lane = tid & 63, w = tid >> 6;
  float rj[16];
  #pragma unroll
  for (int j = 0; j < 16; j++) rj[j] = 1.f / (1024.f * Rin[j*64 + lane]);
  float acc[16];
  #pragma unroll
  for (int j = 0; j < 16; j++) acc[j] = 0.f;
  int row0 = blockIdx.x * 32;
  for (int rr = w; rr < 16; rr += 4) {
    uchar16 a = *(const uchar16*)(S8 + (size_t)(row0 + rr) * 1024 + lane * 16);
    uchar16 b = *(const uchar16*)(S8 + (size_t)(row0 + rr + 16) * 1024 + lane * 16);
    float XA[16], XB[16];
    float csA = 0.f, csB = 0.f;
    #pragma unroll
    for (int j = 0; j < 16; j++) {
      XA[j] = __expf(20.f * e52f(a[j]));
      XB[j] = __expf(20.f * e52f(b[j]));
    }
    #pragma unroll
    for (int j = 0; j < 16; j++) { csA += XA[j]*rj[j]; csB += XB[j]*rj[j]; }
    #pragma unroll
    for (int d = 32; d >= 1; d >>= 1) {
      csA += __shfl_xor(csA, d);
      csB += __shfl_xor(csB, d);
    }
    float cfA = 1.f / (csA * 65536.f), cfB = 1.f / (csB * 65536.f);
    #pragma unroll
    for (int j = 0; j < 16; j++) acc[j] += XA[j]*cfA + XB[j]*cfB;
  }
  #pragma unroll
  for (int j = 0; j < 16; j++) lds[w*1024 + lane + 64*j] = acc[j];
  __syncthreads();
  for (int q = tid; q < 1024; q += 256)
    Pout[(size_t)blockIdx.x * 1024 + q] = lds[q] + lds[1024+q] + lds[2048+q] + lds[3072+q];
}

// ---------------- sinkhorn loss pass; 2-row ILP; lse(10s)=log(sum exp(10s)) (10s<=~10.2, safe)
__global__ __launch_bounds__(256) void k_sinkL(const unsigned char* __restrict__ S8,
                                               const float* __restrict__ Rin,
                                               float* __restrict__ LPout) {
  __shared__ float lr[4];
  int tid = threadIdx.x, lane = tid & 63, w = tid >> 6;
  float rj[16];
  #pragma unroll
  for (int j = 0; j < 16; j++) rj[j] = 1.f / (1024.f * Rin[j*64 + lane]);
  float lsum = 0.f;
  int row0 = blockIdx.x * 32;
  for (int rr = w; rr < 16; rr += 4) {
    uchar16 a = *(const uchar16*)(S8 + (size_t)(row0 + rr) * 1024 + lane * 16);
    uchar16 b = *(const uchar16*)(S8 + (size_t)(row0 + rr + 16) * 1024 + lane * 16);
    float sA[16], sB[16], yA[16], yB[16];
    #pragma unroll
    for (int j = 0; j < 16; j++) {
      sA[j] = e52f(a[j]);
      sB[j] = e52f(b[j]);
    }
    #pragma unroll
    for (int j = 0; j < 16; j++) { yA[j] = __expf(10.f*sA[j]); yB[j] = __expf(10.f*sB[j]); }
    float csA = 0.f, csB = 0.f, tA = 0.f, tB = 0.f, YA = 0.f, YB = 0.f;
    #pragma unroll
    for (int j = 0; j < 16; j++) {
      float xa = yA[j]*yA[j]*rj[j];
      float xb = yB[j]*yB[j]*rj[j];
      csA += xa; tA += xa*sA[j]; YA += yA[j];
      csB += xb; tB += xb*sB[j]; YB += yB[j];
    }
    #pragma unroll
    for (int d = 32; d >= 1; d >>= 1) {
      csA += __shfl_xor(csA, d); csB += __shfl_xor(csB, d);
      tA  += __shfl_xor(tA, d);  tB  += __shfl_xor(tB, d);
      YA  += __shfl_xor(YA, d);  YB  += __shfl_xor(YB, d);
    }
    if (lane == 0)
      lsum += (logf(YA) - 10.f*tA/csA) + (logf(YB) - 10.f*tB/csB);
  }
  if (lane == 0) lr[w] = lsum;
  __syncthreads();
  if (tid == 0) LPout[blockIdx.x] = lr[0]+lr[1]+lr[2]+lr[3];
}

// ---------------- finalize: sum all loss partials, write 5 f32 outputs
__global__ __launch_bounds__(256) void k_final(const float* __restrict__ scal,
                                               const float* __restrict__ PlossP,
                                               const float* __restrict__ NlossP,
                                               const float* __restrict__ PLp,
                                               const float* __restrict__ SLp,
                                               float* __restrict__ out) {
  __shared__ float lr[4];
  int tid = threadIdx.x, lane = tid & 63, w = tid >> 6;
  float tots[4];
  const float* arrs[4] = {PlossP, NlossP, PLp, SLp};
  const int ns[4] = {512, 1024, 256, 2048};
  for (int k = 0; k < 4; k++) {
    float s = 0.f;
    for (int i = tid; i < ns[k]; i += 256) s += arrs[k][i];
    s = wredsum(s);
    __syncthreads();
    if (lane == 0) lr[w] = s;
    __syncthreads();
    tots[k] = lr[0]+lr[1]+lr[2]+lr[3];
  }
  if (tid == 0) {
    float l   = 1.f - tots[0] / 16384.f;
    float ln  = tots[1] / 32768.f;
    float lp  = tots[2] / 65536.f;
    float ul  = tots[3] / 65536.f;
    float rep = scal[4];
    float nl  = 0.5f * (ln + lp);
    float cls = 0.45f*l + 0.3f*nl + 0.1f*ul + 0.15f*rep;
    out[0] = cls;
    out[1] = l;
    out[2] = ul;
    out[3] = nl;
    out[4] = rep;
  }
}

extern "C" void kernel_launch(void* const* d_in, const int* in_sizes, int n_in,
                              void* d_out, int out_size, void* d_ws, size_t ws_size,
                              hipStream_t stream) {
  const float* PF = (const float*)d_in[0];   // p_feats [16384][512]
  const float* UF = (const float*)d_in[1];   // u_feats [65536][512]
  const float* NF = (const float*)d_in[2];   // n_feats [32768][512]
  const float* PC = (const float*)d_in[3];   // positive_center [1][512]
  const float* PU = (const float*)d_in[4];   // proxy_u [1024][512]
  const float* NC = (const float*)d_in[5];   // negative_centers [4][512]

  char* ws = (char*)d_ws;
  const size_t WS_REQUIRED = 202736768ULL;
  if (ws_size < WS_REQUIRED) return;

  float* R1     = (float*)(ws + 0);        // 1024 f32, q-order (zeroed; gemm atomics)
  float* R2     = (float*)(ws + 4096);     // 1024 f32, q-order
  float* R3     = (float*)(ws + 8192);     // 1024 f32, q-order
  float* scal   = (float*)(ws + 12288);    // 16 f32; only [4]=repulsion used
  float* sums   = (float*)(ws + 12416);    // 2048 f32
  float* invP   = (float*)(ws + 20608);    // 1024 f32
  float* UPp    = (float*)(ws + 24704);    // [2048][4]
  float* PPpA   = (float*)(ws + 57472);    // [256][4]
  float* PPpB   = (float*)(ws + 61568);    // [256][4]
  float* PLp    = (float*)(ws + 65664);    // [256]
  float* PlossP = (float*)(ws + 66688);    // [512]
  float* NlossP = (float*)(ws + 68736);    // [1024]
  float* pos_hat   = (float*)(ws + 81024); // 512 f32
  float* negc0_hat = (float*)(ws + 83072); // 2048 f32
  float* negc_hat  = (float*)(ws + 91264); // 2048 f32
  float* invU      = (float*)(ws + 99456); // 65536 f32
  float* SU    = (float*)(ws + 361600);            // [65536][4] f32 (nlup -> psink)
  unsigned short* Ph = (unsigned short*)(ws + 361600); // [1024][512] bf16 (after psink; aliases SU)
  float* SumP = (float*)(ws + 1410176);            // [1024][2048] f32 (8 MB; plns -> redcol)
  unsigned short* Uh = (unsigned short*)(ws + 1410176); // [65536][512] bf16 (nlup -> gemm; after redcol)
  float* SPp  = (float*)(ws + 1410176);            // [2048][1024] f32 (after gemm)
  float* SLp  = (float*)(ws + 9798784);            // [2048] f32 (sinkL; after gemm, Uh dead)
  float* CntP = (float*)(ws + 9806976);            // [1024][4] f32 (plns -> center; before Uh written)
  unsigned char* S8 = (unsigned char*)(ws + 68519040); // [65536][1024] fp8 e5m2 (gemm output, 67 MB)
  float* inv_n = (float*)(ws + 68519040);          // 32768 f32 — inside S8 region; dead before gemm writes S8

  hipMemsetAsync(ws, 0, 4096, stream);  // only R1 needs zeroing (gemm atomics)

  k_prep<<<1, 320, 0, stream>>>(PC, NC, pos_hat, negc0_hat);
  k_plns<<<1536, 256, 0, stream>>>(PF, pos_hat, PlossP, NF, negc0_hat, inv_n, CntP, SumP);
  k_redcol<<<128, 256, 0, stream>>>(SumP, sums, 1024, 2048);
  k_center<<<1, 256, 0, stream>>>(CntP, sums, NC, pos_hat, negc_hat, scal);
  k_nlup<<<3072, 256, 0, stream>>>(NF, inv_n, negc_hat, NlossP, UF, SU, UPp, Uh, invU);

  // pseudo sinkhorn (K=4), partial-in partial-out
  k_psink<<<256, 256, 0, stream>>>(SU, UPp, 2048, PPpA, nullptr, 1);
  k_psink<<<256, 256, 0, stream>>>(SU, PPpA, 256, PPpB, nullptr, 1);
  k_psink<<<256, 256, 0, stream>>>(SU, PPpB, 256, nullptr, PLp, 2);

  k_rownormP<<<32, 256, 0, stream>>>(PU, Ph, invP, 1024);  // Ph overlaps dead SU

  // u branch: GEMM (fp8 S) + 3 sinkhorn passes with partial-based column reduction
  k_gemm<<<2048, 512, 0, stream>>>(Uh, Ph, invU, invP, S8, R1);
  k_sink1<<<2048, 256, 0, stream>>>(S8, R1, SPp);
  k_redcol<<<64, 256, 0, stream>>>(SPp, R2, 2048, 1024);
  k_sink1<<<2048, 256, 0, stream>>>(S8, R2, SPp);
  k_redcol<<<64, 256, 0, stream>>>(SPp, R3, 2048, 1024);
  k_sinkL<<<2048, 256, 0, stream>>>(S8, R3, SLp);

  k_final<<<1, 256, 0, stream>>>(scal, PlossP, NlossP, PLp, SLp, (float*)d_out);
}